// Round 2
// baseline (1045.917 us; speedup 1.0000x reference)
//
#include <hip/hip_runtime.h>
#include <hip/hip_bf16.h>
#include <math.h>

#define B_ 2
#define L_ 2048
#define D_ 2048
#define H_ 16
#define HD_ 128
#define E_ (B_*L_*D_)   // 8388608
#define W_ (D_*D_)      // 4194304

typedef __bf16 bf16;
typedef __bf16 bf16x8 __attribute__((ext_vector_type(8)));
typedef __bf16 bf16x4 __attribute__((ext_vector_type(4)));
typedef float  f32x4  __attribute__((ext_vector_type(4)));

// ---------------- f32 -> bf16 convert ----------------
__global__ void cvt_f32_bf16(const float* __restrict__ src, bf16* __restrict__ dst, int n) {
  int i = (blockIdx.x * blockDim.x + threadIdx.x) * 4;
  if (i + 3 < n) {
    f32x4 v = *reinterpret_cast<const f32x4*>(src + i);
    bf16x4 o;
    o[0] = (bf16)v[0]; o[1] = (bf16)v[1]; o[2] = (bf16)v[2]; o[3] = (bf16)v[3];
    *reinterpret_cast<bf16x4*>(dst + i) = o;
  }
}

// ---------------- RoPE cos/sin table: [L][64] ----------------
__global__ void rope_table(float* __restrict__ ct, float* __restrict__ st) {
  int t = blockIdx.x;
  int i = threadIdx.x;
  float inv = powf(10000.0f, -2.0f * (float)i / 128.0f);
  float f = (float)t * inv;
  ct[t * 64 + i] = cosf(f);
  st[t * 64 + i] = sinf(f);
}

// ---------------- in-place RoPE on Q and K ----------------
__global__ void rope_inplace(bf16* __restrict__ Q, bf16* __restrict__ Kt,
                             const float* __restrict__ ct, const float* __restrict__ st) {
  size_t idx = (size_t)blockIdx.x * blockDim.x + threadIdx.x;
  const size_t per = E_ / 8;
  bf16* P = (idx < per) ? Q : Kt;
  size_t li = ((idx < per) ? idx : idx - per) * 8;
  int l   = (int)((li / D_) % L_);
  int col = (int)(li % D_);
  int i0  = (col & 127) >> 1;
  bf16x8 v = *reinterpret_cast<const bf16x8*>(P + li);
  f32x4 c4 = *reinterpret_cast<const f32x4*>(ct + l * 64 + i0);
  f32x4 s4 = *reinterpret_cast<const f32x4*>(st + l * 64 + i0);
  bf16x8 o;
#pragma unroll
  for (int p = 0; p < 4; ++p) {
    float x1 = (float)v[2*p], x2 = (float)v[2*p+1];
    o[2*p]   = (bf16)(x1 * c4[p] - x2 * s4[p]);
    o[2*p+1] = (bf16)(x1 * s4[p] + x2 * c4[p]);
  }
  *reinterpret_cast<bf16x8*>(P + li) = o;
}

// ---------------- V (b,l,h*128+d) -> Vt (b,h,d,l) tiled transpose ----------------
__global__ void transpose_v(const bf16* __restrict__ Vraw, bf16* __restrict__ Vt) {
  __shared__ bf16 tile[32][33];
  int bh = blockIdx.z; int b = bh >> 4, h = bh & 15;
  int l0 = blockIdx.x * 32, d0 = blockIdx.y * 32;
  int tx = threadIdx.x, ty = threadIdx.y;
#pragma unroll
  for (int j = 0; j < 4; ++j) {
    int r = ty + j * 8;
    tile[r][tx] = Vraw[((size_t)b * L_ + l0 + r) * D_ + h * HD_ + d0 + tx];
  }
  __syncthreads();
#pragma unroll
  for (int j = 0; j < 4; ++j) {
    int r = ty + j * 8;
    Vt[((size_t)bh * HD_ + d0 + r) * L_ + l0 + tx] = tile[tx][r];
  }
}

// ---------------- zero cols >= 64-aligned diagonal boundary ----------------
__global__ void zero_upper(float* __restrict__ attn) {
  int l = blockIdx.x, bh = blockIdx.y;
  int z0 = ((l >> 6) + 1) << 6;
  float* row = attn + ((size_t)bh * L_ + l) * L_;
  for (int c = z0 + threadIdx.x * 4; c < L_; c += 256 * 4) {
    *reinterpret_cast<f32x4*>(row + c) = (f32x4){0.f, 0.f, 0.f, 0.f};
  }
}

// ---------------- GEMM: C[M,N] = A[M,K] @ Bw[N,K]^T, reg-prefetch pipelined ----------------
template<int OUT_BF16>
__global__ __launch_bounds__(256) void gemm_bt(const bf16* __restrict__ A,
                                               const bf16* __restrict__ Bw,
                                               void* __restrict__ Cout,
                                               int M, int N, int K) {
  __shared__ bf16 As[128][72];
  __shared__ bf16 Bs[128][72];
  const int tid = threadIdx.x;
  const int lane = tid & 63;
  const int w = tid >> 6;
  const int l15 = lane & 15, g = lane >> 4;
  const int m0 = blockIdx.y * 128, n0 = blockIdx.x * 128;
  const int wm = (w >> 1) * 64, wn = (w & 1) * 64;

  f32x4 acc[4][4];
#pragma unroll
  for (int m = 0; m < 4; ++m)
#pragma unroll
    for (int n = 0; n < 4; ++n) acc[m][n] = (f32x4){0.f, 0.f, 0.f, 0.f};

  bf16x8 ra[4], rb[4];
#pragma unroll
  for (int i = 0; i < 4; ++i) {
    int chunk = tid + 256 * i;
    int r_ = chunk >> 3, c8 = (chunk & 7) * 8;
    ra[i] = *reinterpret_cast<const bf16x8*>(A  + (size_t)(m0 + r_) * K + c8);
    rb[i] = *reinterpret_cast<const bf16x8*>(Bw + (size_t)(n0 + r_) * K + c8);
  }

  for (int kt = 0; kt < K; kt += 64) {
    __syncthreads();   // all waves done reading LDS (prev iter)
#pragma unroll
    for (int i = 0; i < 4; ++i) {
      int chunk = tid + 256 * i;
      int r_ = chunk >> 3, c8 = (chunk & 7) * 8;
      *reinterpret_cast<bf16x8*>(&As[r_][c8]) = ra[i];
      *reinterpret_cast<bf16x8*>(&Bs[r_][c8]) = rb[i];
    }
    __syncthreads();
    if (kt + 64 < K) {   // prefetch next tile; latency hides under MFMA below
#pragma unroll
      for (int i = 0; i < 4; ++i) {
        int chunk = tid + 256 * i;
        int r_ = chunk >> 3, c8 = (chunk & 7) * 8;
        ra[i] = *reinterpret_cast<const bf16x8*>(A  + (size_t)(m0 + r_) * K + kt + 64 + c8);
        rb[i] = *reinterpret_cast<const bf16x8*>(Bw + (size_t)(n0 + r_) * K + kt + 64 + c8);
      }
    }
#pragma unroll
    for (int kk = 0; kk < 64; kk += 32) {
      bf16x8 af[4], bfr[4];
#pragma unroll
      for (int m = 0; m < 4; ++m)
        af[m] = *reinterpret_cast<const bf16x8*>(&As[wm + m * 16 + l15][kk + g * 8]);
#pragma unroll
      for (int n = 0; n < 4; ++n)
        bfr[n] = *reinterpret_cast<const bf16x8*>(&Bs[wn + n * 16 + l15][kk + g * 8]);
#pragma unroll
      for (int m = 0; m < 4; ++m)
#pragma unroll
        for (int n = 0; n < 4; ++n)
          acc[m][n] = __builtin_amdgcn_mfma_f32_16x16x32_bf16(af[m], bfr[n], acc[m][n], 0, 0, 0);
    }
  }
#pragma unroll
  for (int m = 0; m < 4; ++m) {
    int orow = m0 + wm + m * 16 + g * 4;
#pragma unroll
    for (int n = 0; n < 4; ++n) {
      int col = n0 + wn + n * 16 + l15;
#pragma unroll
      for (int r = 0; r < 4; ++r) {
        if (OUT_BF16) ((bf16*)Cout)[(size_t)(orow + r) * N + col] = (bf16)acc[m][n][r];
        else          ((float*)Cout)[(size_t)(orow + r) * N + col] = acc[m][n][r];
      }
    }
  }
}

// ---------------- fused causal attention, max-free softmax ----------------
// grid (L/64, B*H), block 256 (4 waves x 16 q rows); qblk reversed for load balance
__global__ __launch_bounds__(256) void attn_fused(const bf16* __restrict__ Qb,
                                                  const bf16* __restrict__ Kb,
                                                  const bf16* __restrict__ Vt,
                                                  float* __restrict__ attn,
                                                  bf16* __restrict__ Oh) {
  __shared__ bf16 Plds[4][16][72];   // per-wave 16q x 64k, +8 pad
  const int tid = threadIdx.x;
  const int w = tid >> 6, lane = tid & 63;
  const int l15 = lane & 15, g = lane >> 4;
  const int bh = blockIdx.y, b = bh >> 4, h = bh & 15;
  const int qblk = gridDim.x - 1 - blockIdx.x;    // heavy blocks dispatch first
  const int q0 = qblk * 64 + w * 16;
  const float scale = 0.08838834764831845f;       // 1/sqrt(128)
  const int nt64 = qblk + 1;                      // 64-wide K groups

  const bf16* qrow = Qb + ((size_t)b * L_ + q0 + l15) * D_ + h * HD_;
  bf16x8 qf[4];
#pragma unroll
  for (int c = 0; c < 4; ++c)
    qf[c] = *reinterpret_cast<const bf16x8*>(qrow + c * 32 + g * 8);

  const bf16* kbase = Kb + ((size_t)b * L_) * D_ + h * HD_;

  // ---- pass 1: per-lane partial rowsums of exp (no max, no per-tile reduce) ----
  float sum[4] = {0.f, 0.f, 0.f, 0.f};
  for (int grp = 0; grp < nt64; ++grp) {
    int k0g = grp * 64;
    f32x4 acc[4];
#pragma unroll
    for (int t = 0; t < 4; ++t) acc[t] = (f32x4){0.f, 0.f, 0.f, 0.f};
#pragma unroll
    for (int t = 0; t < 4; ++t) {
      const bf16* krow = kbase + (size_t)(k0g + t * 16 + l15) * D_;
#pragma unroll
      for (int c = 0; c < 4; ++c) {
        bf16x8 kf = *reinterpret_cast<const bf16x8*>(krow + c * 32 + g * 8);
        acc[t] = __builtin_amdgcn_mfma_f32_16x16x32_bf16(qf[c], kf, acc[t], 0, 0, 0);
      }
    }
    if (grp < nt64 - 1) {
#pragma unroll
      for (int t = 0; t < 4; ++t)
#pragma unroll
        for (int r = 0; r < 4; ++r)
          sum[r] += __expf(acc[t][r] * scale);
    } else {
#pragma unroll
      for (int t = 0; t < 4; ++t)
#pragma unroll
        for (int r = 0; r < 4; ++r) {
          int qr = q0 + g * 4 + r;
          int kc = k0g + t * 16 + l15;
          sum[r] += (kc <= qr) ? __expf(acc[t][r] * scale) : 0.f;
        }
    }
  }
#pragma unroll
  for (int r = 0; r < 4; ++r) {
#pragma unroll
    for (int sh = 1; sh < 16; sh <<= 1)
      sum[r] += __shfl_xor(sum[r], sh, 64);
  }
  float rinv[4];
#pragma unroll
  for (int r = 0; r < 4; ++r) rinv[r] = 1.0f / sum[r];

  // ---- pass 2: recompute S, write normalized P, accumulate PV ----
  f32x4 oacc[8];
#pragma unroll
  for (int t8 = 0; t8 < 8; ++t8) oacc[t8] = (f32x4){0.f, 0.f, 0.f, 0.f};

  float* arow = attn + ((size_t)bh * L_ + q0) * L_;
  const bf16* vbase = Vt + (size_t)bh * HD_ * L_;

  for (int grp = 0; grp < nt64; ++grp) {
    int k0g = grp * 64;
#pragma unroll
    for (int t = 0; t < 4; ++t) {
      f32x4 acc = (f32x4){0.f, 0.f, 0.f, 0.f};
      const bf16* krow = kbase + (size_t)(k0g + t * 16 + l15) * D_;
#pragma unroll
      for (int c = 0; c < 4; ++c) {
        bf16x8 kf = *reinterpret_cast<const bf16x8*>(krow + c * 32 + g * 8);
        acc = __builtin_amdgcn_mfma_f32_16x16x32_bf16(qf[c], kf, acc, 0, 0, 0);
      }
      if (grp < nt64 - 1) {
#pragma unroll
        for (int r = 0; r < 4; ++r) {
          float p = __expf(acc[r] * scale) * rinv[r];
          arow[(size_t)(g * 4 + r) * L_ + k0g + t * 16 + l15] = p;
          Plds[w][g * 4 + r][t * 16 + l15] = (bf16)p;
        }
      } else {
#pragma unroll
        for (int r = 0; r < 4; ++r) {
          int qr = q0 + g * 4 + r;
          int kc = k0g + t * 16 + l15;
          float p = (kc <= qr) ? __expf(acc[r] * scale) * rinv[r] : 0.f;
          arow[(size_t)(g * 4 + r) * L_ + k0g + t * 16 + l15] = p;
          Plds[w][g * 4 + r][t * 16 + l15] = (bf16)p;
        }
      }
    }
    asm volatile("s_waitcnt lgkmcnt(0)" ::: "memory");
#pragma unroll
    for (int ck = 0; ck < 2; ++ck) {
      bf16x8 pa = *reinterpret_cast<const bf16x8*>(&Plds[w][l15][ck * 32 + g * 8]);
#pragma unroll
      for (int t8 = 0; t8 < 8; ++t8) {
        const bf16* vrow = vbase + (size_t)(t8 * 16 + l15) * L_ + k0g + ck * 32 + g * 8;
        bf16x8 vf = *reinterpret_cast<const bf16x8*>(vrow);
        oacc[t8] = __builtin_amdgcn_mfma_f32_16x16x32_bf16(pa, vf, oacc[t8], 0, 0, 0);
      }
    }
    asm volatile("s_waitcnt lgkmcnt(0)" ::: "memory");   // P reads done before next grp writes
  }

  bf16* orow = Oh + ((size_t)b * L_ + q0) * D_ + h * HD_;
#pragma unroll
  for (int t8 = 0; t8 < 8; ++t8)
#pragma unroll
    for (int r = 0; r < 4; ++r)
      orow[(size_t)(g * 4 + r) * D_ + t8 * 16 + l15] = (bf16)oacc[t8][r];
}

// ---------------- host ----------------
extern "C" void kernel_launch(void* const* d_in, const int* in_sizes, int n_in,
                              void* d_out, int out_size, void* d_ws, size_t ws_size,
                              hipStream_t stream) {
  const float* x_q  = (const float*)d_in[0];
  const float* x_kv = (const float*)d_in[1];
  const float* w_q = (const float*)d_in[3];
  const float* w_k = (const float*)d_in[4];
  const float* w_v = (const float*)d_in[5];
  const float* w_o = (const float*)d_in[6];

  char* p = (char*)d_ws;
  auto alloc = [&](size_t bytes) { char* r = p; p += (bytes + 255) & ~(size_t)255; return r; };
  bf16* xq_b  = (bf16*)alloc((size_t)E_ * 2);
  bf16* xkv_b = (bf16*)alloc((size_t)E_ * 2);
  bf16* wq_b  = (bf16*)alloc((size_t)W_ * 2);
  bf16* wk_b  = (bf16*)alloc((size_t)W_ * 2);
  bf16* wv_b  = (bf16*)alloc((size_t)W_ * 2);
  bf16* wo_b  = (bf16*)alloc((size_t)W_ * 2);
  bf16* Qraw  = (bf16*)alloc((size_t)E_ * 2);
  bf16* Kraw  = (bf16*)alloc((size_t)E_ * 2);
  bf16* Vraw  = (bf16*)alloc((size_t)E_ * 2);
  bf16* Vt    = (bf16*)alloc((size_t)E_ * 2);
  bf16* Oh    = (bf16*)alloc((size_t)E_ * 2);
  float* ct   = (float*)alloc((size_t)L_ * 64 * 4);
  float* st2  = (float*)alloc((size_t)L_ * 64 * 4);

  float* out0     = (float*)d_out;
  float* attn_out = out0 + E_;

  cvt_f32_bf16<<<8192, 256, 0, stream>>>(x_q,  xq_b,  E_);
  cvt_f32_bf16<<<8192, 256, 0, stream>>>(x_kv, xkv_b, E_);
  cvt_f32_bf16<<<4096, 256, 0, stream>>>(w_q, wq_b, W_);
  cvt_f32_bf16<<<4096, 256, 0, stream>>>(w_k, wk_b, W_);
  cvt_f32_bf16<<<4096, 256, 0, stream>>>(w_v, wv_b, W_);
  cvt_f32_bf16<<<4096, 256, 0, stream>>>(w_o, wo_b, W_);
  rope_table<<<L_, 64, 0, stream>>>(ct, st2);

  gemm_bt<1><<<dim3(16, 32), 256, 0, stream>>>(xq_b,  wq_b, Qraw, B_*L_, D_, D_);
  gemm_bt<1><<<dim3(16, 32), 256, 0, stream>>>(xkv_b, wk_b, Kraw, B_*L_, D_, D_);
  gemm_bt<1><<<dim3(16, 32), 256, 0, stream>>>(xkv_b, wv_b, Vraw, B_*L_, D_, D_);

  rope_inplace<<<8192, 256, 0, stream>>>(Qraw, Kraw, ct, st2);
  transpose_v<<<dim3(64, 4, 32), dim3(32, 8), 0, stream>>>(Vraw, Vt);
  zero_upper<<<dim3(2048, 32), 256, 0, stream>>>(attn_out);
  attn_fused<<<dim3(32, 32), 256, 0, stream>>>(Qraw, Kraw, Vt, attn_out, Oh);
  gemm_bt<0><<<dim3(16, 32), 256, 0, stream>>>(Oh, wo_b, out0, B_*L_, D_, D_);
}

// Round 3
// 488.919 us; speedup vs baseline: 2.1392x; 2.1392x over previous
//
#include <hip/hip_runtime.h>
#include <hip/hip_bf16.h>
#include <math.h>

#define B_ 2
#define L_ 2048
#define D_ 2048
#define H_ 16
#define HD_ 128
#define E_ (B_*L_*D_)   // 8388608
#define W_ (D_*D_)      // 4194304

typedef __bf16 bf16;
typedef __bf16 bf16x8 __attribute__((ext_vector_type(8)));
typedef __bf16 bf16x4 __attribute__((ext_vector_type(4)));
typedef float  f32x4  __attribute__((ext_vector_type(4)));

// async global->LDS, 16B per lane; lds ptr must be wave-uniform
#define GLL16(gp_, lp_) __builtin_amdgcn_global_load_lds( \
    (const __attribute__((address_space(1))) void*)(gp_), \
    (__attribute__((address_space(3))) void*)(lp_), 16, 0, 0)

#define BARRIER() do { asm volatile("" ::: "memory"); \
    __builtin_amdgcn_s_barrier(); \
    asm volatile("" ::: "memory"); } while (0)

// ---------------- f32 -> bf16 convert ----------------
__global__ void cvt_f32_bf16(const float* __restrict__ src, bf16* __restrict__ dst, int n) {
  int i = (blockIdx.x * blockDim.x + threadIdx.x) * 4;
  if (i + 3 < n) {
    f32x4 v = *reinterpret_cast<const f32x4*>(src + i);
    bf16x4 o;
    o[0] = (bf16)v[0]; o[1] = (bf16)v[1]; o[2] = (bf16)v[2]; o[3] = (bf16)v[3];
    *reinterpret_cast<bf16x4*>(dst + i) = o;
  }
}

// ---------------- RoPE cos/sin table: [L][64] ----------------
__global__ void rope_table(float* __restrict__ ct, float* __restrict__ st) {
  int t = blockIdx.x;
  int i = threadIdx.x;
  float inv = powf(10000.0f, -2.0f * (float)i / 128.0f);
  float f = (float)t * inv;
  ct[t * 64 + i] = cosf(f);
  st[t * 64 + i] = sinf(f);
}

// ---------------- in-place RoPE on Q and K ----------------
__global__ void rope_inplace(bf16* __restrict__ Q, bf16* __restrict__ Kt,
                             const float* __restrict__ ct, const float* __restrict__ st) {
  size_t idx = (size_t)blockIdx.x * blockDim.x + threadIdx.x;
  const size_t per = E_ / 8;
  bf16* P = (idx < per) ? Q : Kt;
  size_t li = ((idx < per) ? idx : idx - per) * 8;
  int l   = (int)((li / D_) % L_);
  int col = (int)(li % D_);
  int i0  = (col & 127) >> 1;
  bf16x8 v = *reinterpret_cast<const bf16x8*>(P + li);
  f32x4 c4 = *reinterpret_cast<const f32x4*>(ct + l * 64 + i0);
  f32x4 s4 = *reinterpret_cast<const f32x4*>(st + l * 64 + i0);
  bf16x8 o;
#pragma unroll
  for (int p = 0; p < 4; ++p) {
    float x1 = (float)v[2*p], x2 = (float)v[2*p+1];
    o[2*p]   = (bf16)(x1 * c4[p] - x2 * s4[p]);
    o[2*p+1] = (bf16)(x1 * s4[p] + x2 * c4[p]);
  }
  *reinterpret_cast<bf16x8*>(P + li) = o;
}

// ---------------- V (b,l,h*128+d) -> Vt (b,h,d,l) tiled transpose ----------------
__global__ void transpose_v(const bf16* __restrict__ Vraw, bf16* __restrict__ Vt) {
  __shared__ bf16 tile[32][33];
  int bh = blockIdx.z; int b = bh >> 4, h = bh & 15;
  int l0 = blockIdx.x * 32, d0 = blockIdx.y * 32;
  int tx = threadIdx.x, ty = threadIdx.y;
#pragma unroll
  for (int j = 0; j < 4; ++j) {
    int r = ty + j * 8;
    tile[r][tx] = Vraw[((size_t)b * L_ + l0 + r) * D_ + h * HD_ + d0 + tx];
  }
  __syncthreads();
#pragma unroll
  for (int j = 0; j < 4; ++j) {
    int r = ty + j * 8;
    Vt[((size_t)bh * HD_ + d0 + r) * L_ + l0 + tx] = tile[tx][r];
  }
}

// ---------------- zero cols >= 64-aligned diagonal boundary ----------------
__global__ void zero_upper(float* __restrict__ attn) {
  int l = blockIdx.x, bh = blockIdx.y;
  int z0 = ((l >> 6) + 1) << 6;
  float* row = attn + ((size_t)bh * L_ + l) * L_;
  for (int c = z0 + threadIdx.x * 4; c < L_; c += 256 * 4) {
    *reinterpret_cast<f32x4*>(row + c) = (f32x4){0.f, 0.f, 0.f, 0.f};
  }
}

// ---------------- GEMM: C[M,N] = A[M,K] @ Bw[N,K]^T (m97 structure) ----------------
// 128x128 tile, BK=64, global_load_lds staging, XOR-swizzled LDS
template<int OUT_BF16>
__global__ __launch_bounds__(256, 4) void gemm_bt(const bf16* __restrict__ A,
                                                  const bf16* __restrict__ Bw,
                                                  void* __restrict__ Cout,
                                                  int M, int N, int K) {
  __shared__ bf16 As[128 * 64];   // linear; content XOR-swizzled per 16B chunk
  __shared__ bf16 Bs[128 * 64];
  const int tid = threadIdx.x;
  const int lane = tid & 63;
  const int w = tid >> 6;
  const int l15 = lane & 15, lg = lane >> 4;
  const int m0 = blockIdx.y * 128, n0 = blockIdx.x * 128;
  const int wm = (w >> 1) * 64, wn = (w & 1) * 64;

  // staging lane constants: 4 calls x 256 threads = 1024 chunks (128 rows x 8 chunks)
  int rowS[4], schS[4];
#pragma unroll
  for (int s = 0; s < 4; ++s) {
    int cl = s * 256 + tid;
    rowS[s] = cl >> 3;
    schS[s] = ((cl & 7) ^ ((cl >> 3) & 7)) << 3;   // element offset of swizzled source chunk
  }

  f32x4 acc[4][4];
#pragma unroll
  for (int m = 0; m < 4; ++m)
#pragma unroll
    for (int n = 0; n < 4; ++n) acc[m][n] = (f32x4){0.f, 0.f, 0.f, 0.f};

  for (int kt = 0; kt < K; kt += 64) {
    __syncthreads();                     // prev iter's LDS reads done
#pragma unroll
    for (int s = 0; s < 4; ++s) {
      GLL16(A  + (size_t)(m0 + rowS[s]) * K + kt + schS[s], As + s * 2048 + w * 512);
      GLL16(Bw + (size_t)(n0 + rowS[s]) * K + kt + schS[s], Bs + s * 2048 + w * 512);
    }
    __syncthreads();                     // implicit vmcnt(0) drains the gll writes
#pragma unroll
    for (int kk = 0; kk < 64; kk += 32) {
      bf16x8 af[4], bfr[4];
#pragma unroll
      for (int m = 0; m < 4; ++m)
        af[m] = *reinterpret_cast<const bf16x8*>(
            As + (wm + m * 16 + l15) * 64 + ((((kk >> 3) + lg) ^ (l15 & 7)) << 3));
#pragma unroll
      for (int n = 0; n < 4; ++n)
        bfr[n] = *reinterpret_cast<const bf16x8*>(
            Bs + (wn + n * 16 + l15) * 64 + ((((kk >> 3) + lg) ^ (l15 & 7)) << 3));
#pragma unroll
      for (int m = 0; m < 4; ++m)
#pragma unroll
        for (int n = 0; n < 4; ++n)
          acc[m][n] = __builtin_amdgcn_mfma_f32_16x16x32_bf16(af[m], bfr[n], acc[m][n], 0, 0, 0);
    }
  }
#pragma unroll
  for (int m = 0; m < 4; ++m) {
    int orow = m0 + wm + m * 16 + lg * 4;
#pragma unroll
    for (int n = 0; n < 4; ++n) {
      int col = n0 + wn + n * 16 + l15;
#pragma unroll
      for (int r = 0; r < 4; ++r) {
        if (OUT_BF16) ((bf16*)Cout)[(size_t)(orow + r) * N + col] = (bf16)acc[m][n][r];
        else          ((float*)Cout)[(size_t)(orow + r) * N + col] = acc[m][n][r];
      }
    }
  }
}

// ---------------- fused causal attention ----------------
// grid (16, B*H), block 512 (8 waves). Waves 0-3: 64-row q-tile x; waves 4-7: tile 31-x.
// K double-buffered LDS, V single-buffered; global_load_lds + counted vmcnt + raw barriers.
__global__ __launch_bounds__(512, 4) void attn_fused(const bf16* __restrict__ Qb,
                                                     const bf16* __restrict__ Kb,
                                                     const bf16* __restrict__ Vt,
                                                     float* __restrict__ attn,
                                                     bf16* __restrict__ Oh) {
  __shared__ bf16 Klds[2][64 * 128];   // 32 KB, swizzled content
  __shared__ bf16 Vlds[128 * 64];      // 16 KB, swizzled content
  __shared__ bf16 Plds[8][16][72];     // 18 KB per-wave P

  const int tid = threadIdx.x;
  const int w = tid >> 6, lane = tid & 63;
  const int l15 = lane & 15, lg = lane >> 4;
  const int bh = blockIdx.y, b = bh >> 4, h = bh & 15;
  const int x = blockIdx.x;                 // 0..15
  const int qt = (w < 4) ? x : (31 - x);    // this wave's 64-row tile index
  const int q0w = qt * 64 + (w & 3) * 16;   // wave's first q row
  const int ntW = qt + 1;                   // groups this wave computes
  const int ntB = 32 - x;                   // groups the block stages (max over waves)
  const float sc2 = 0.08838834764831845f * 1.44269504088896f;  // scale * log2(e)

  const bf16* kb = Kb + ((size_t)b * L_) * D_ + h * HD_;
  const bf16* vb = Vt + (size_t)bh * HD_ * L_;

  bf16x8 qf[4];
  {
    const bf16* qrow = Qb + ((size_t)b * L_ + q0w + l15) * D_ + h * HD_;
#pragma unroll
    for (int c = 0; c < 4; ++c)
      qf[c] = *reinterpret_cast<const bf16x8*>(qrow + c * 32 + lg * 8);
  }

  // staging lane constants (2 calls each; 512 threads)
  const int t1 = 512 + tid;
  const int rK0 = tid >> 4, sK0 = ((tid & 15) ^ (rK0 & 7)) << 3;
  const int rK1 = t1 >> 4,  sK1 = ((t1 & 15) ^ (rK1 & 7)) << 3;
  const int rV0 = tid >> 3, sV0 = ((tid & 7) ^ (rV0 & 7)) << 3;
  const int rV1 = t1 >> 3,  sV1 = ((t1 & 7) ^ (rV1 & 7)) << 3;
  bf16* ldsK0 = &Klds[0][0] + w * 512;          // wave-uniform bases
  bf16* ldsK1 = &Klds[0][0] + 4096 + w * 512;
  bf16* ldsV0 = Vlds + w * 512;
  bf16* ldsV1 = Vlds + 4096 + w * 512;

  auto stageK = [&](int gp, int buf) {
    GLL16(kb + (size_t)(gp * 64 + rK0) * D_ + sK0, ldsK0 + buf * 8192);
    GLL16(kb + (size_t)(gp * 64 + rK1) * D_ + sK1, ldsK1 + buf * 8192);
  };
  auto stageV = [&](int gp) {
    GLL16(vb + (size_t)rV0 * L_ + gp * 64 + sV0, ldsV0);
    GLL16(vb + (size_t)rV1 * L_ + gp * 64 + sV1, ldsV1);
  };
  auto qkt = [&](const bf16* kl, f32x4* acc) {
#pragma unroll
    for (int c = 0; c < 4; ++c)
#pragma unroll
      for (int t = 0; t < 4; ++t) {
        bf16x8 kf = *reinterpret_cast<const bf16x8*>(
            kl + (t * 16 + l15) * 128 + ((((c << 2) + lg) ^ (l15 & 7)) << 3));
        acc[t] = __builtin_amdgcn_mfma_f32_16x16x32_bf16(qf[c], kf, acc[t], 0, 0, 0);
      }
  };

  // ================= phase 1: row sums =================
  float sum[4] = {0.f, 0.f, 0.f, 0.f};
  stageK(0, 0);
  for (int gp = 0; gp < ntB; ++gp) {
    BARRIER();                                   // A: prev QK reads done everywhere
    if (gp + 1 < ntB) {
      stageK(gp + 1, (gp + 1) & 1);
      asm volatile("s_waitcnt vmcnt(2)" ::: "memory");   // K(gp) landed
    } else {
      asm volatile("s_waitcnt vmcnt(0)" ::: "memory");
    }
    BARRIER();                                   // B: all waves' K slices landed
    if (gp < ntW) {
      f32x4 acc[4] = {(f32x4){0,0,0,0},(f32x4){0,0,0,0},(f32x4){0,0,0,0},(f32x4){0,0,0,0}};
      qkt(&Klds[gp & 1][0], acc);
      if (gp < qt) {
#pragma unroll
        for (int t = 0; t < 4; ++t)
#pragma unroll
          for (int r = 0; r < 4; ++r)
            sum[r] += exp2f(acc[t][r] * sc2);
      } else {
#pragma unroll
        for (int t = 0; t < 4; ++t)
#pragma unroll
          for (int r = 0; r < 4; ++r) {
            int kc = gp * 64 + t * 16 + l15;
            int qr = q0w + lg * 4 + r;
            sum[r] += (kc <= qr) ? exp2f(acc[t][r] * sc2) : 0.f;
          }
      }
    }
  }
#pragma unroll
  for (int r = 0; r < 4; ++r) {
#pragma unroll
    for (int sh = 1; sh < 16; sh <<= 1)
      sum[r] += __shfl_xor(sum[r], sh, 64);
  }
  float rinv[4];
#pragma unroll
  for (int r = 0; r < 4; ++r) rinv[r] = 1.0f / sum[r];

  // ================= phase 2: write P, accumulate PV =================
  f32x4 oacc[8];
#pragma unroll
  for (int i = 0; i < 8; ++i) oacc[i] = (f32x4){0.f, 0.f, 0.f, 0.f};
  float* arow = attn + ((size_t)bh * L_ + q0w) * L_;

  BARRIER();                                     // phase boundary: Klds reusable
  stageK(0, 0);
  for (int gp = 0; gp < ntB; ++gp) {
    BARRIER();                                   // A: prev PV reads done -> Vlds reusable
    stageV(gp);
    if (gp + 1 < ntB) {
      stageK(gp + 1, (gp + 1) & 1);
      asm volatile("s_waitcnt vmcnt(4)" ::: "memory");   // K(gp) + old stores drained
    } else {
      asm volatile("s_waitcnt vmcnt(2)" ::: "memory");
    }
    BARRIER();                                   // B: K(gp) visible to all
    const bool act = gp < ntW;
    float pv[4][4];
    if (act) {
      f32x4 acc[4] = {(f32x4){0,0,0,0},(f32x4){0,0,0,0},(f32x4){0,0,0,0},(f32x4){0,0,0,0}};
      qkt(&Klds[gp & 1][0], acc);
      if (gp < qt) {
#pragma unroll
        for (int t = 0; t < 4; ++t)
#pragma unroll
          for (int r = 0; r < 4; ++r)
            pv[t][r] = exp2f(acc[t][r] * sc2) * rinv[r];
      } else {
#pragma unroll
        for (int t = 0; t < 4; ++t)
#pragma unroll
          for (int r = 0; r < 4; ++r) {
            int kc = gp * 64 + t * 16 + l15;
            int qr = q0w + lg * 4 + r;
            pv[t][r] = (kc <= qr) ? exp2f(acc[t][r] * sc2) * rinv[r] : 0.f;
          }
      }
#pragma unroll
      for (int t = 0; t < 4; ++t)
#pragma unroll
        for (int r = 0; r < 4; ++r)
          Plds[w][lg * 4 + r][t * 16 + l15] = (bf16)pv[t][r];
    }
    if (gp + 1 < ntB) asm volatile("s_waitcnt vmcnt(2)" ::: "memory");  // V(gp) landed
    else              asm volatile("s_waitcnt vmcnt(0)" ::: "memory");
    if (act) {        // stores AFTER the counted wait -> they drain during PV
#pragma unroll
      for (int t = 0; t < 4; ++t)
#pragma unroll
        for (int r = 0; r < 4; ++r)
          arow[(size_t)(lg * 4 + r) * L_ + gp * 64 + t * 16 + l15] = pv[t][r];
    }
    BARRIER();                                   // C: V(gp) visible to all
    if (act) {
#pragma unroll
      for (int ck = 0; ck < 2; ++ck) {
        bf16x8 pa = *reinterpret_cast<const bf16x8*>(&Plds[w][l15][ck * 32 + lg * 8]);
#pragma unroll
        for (int t8 = 0; t8 < 8; ++t8) {
          bf16x8 vf = *reinterpret_cast<const bf16x8*>(
              Vlds + (t8 * 16 + l15) * 64 + ((((ck << 2) + lg) ^ (l15 & 7)) << 3));
          oacc[t8] = __builtin_amdgcn_mfma_f32_16x16x32_bf16(pa, vf, oacc[t8], 0, 0, 0);
        }
      }
    }
  }

  bf16* orow = Oh + ((size_t)b * L_ + q0w) * D_ + h * HD_;
#pragma unroll
  for (int t8 = 0; t8 < 8; ++t8)
#pragma unroll
    for (int r = 0; r < 4; ++r)
      orow[(size_t)(lg * 4 + r) * D_ + t8 * 16 + l15] = (bf16)oacc[t8][r];
}

// ---------------- host ----------------
extern "C" void kernel_launch(void* const* d_in, const int* in_sizes, int n_in,
                              void* d_out, int out_size, void* d_ws, size_t ws_size,
                              hipStream_t stream) {
  const float* x_q  = (const float*)d_in[0];
  const float* x_kv = (const float*)d_in[1];
  const float* w_q = (const float*)d_in[3];
  const float* w_k = (const float*)d_in[4];
  const float* w_v = (const float*)d_in[5];
  const float* w_o = (const float*)d_in[6];

  char* p = (char*)d_ws;
  auto alloc = [&](size_t bytes) { char* r = p; p += (bytes + 255) & ~(size_t)255; return r; };
  bf16* xq_b  = (bf16*)alloc((size_t)E_ * 2);
  bf16* xkv_b = (bf16*)alloc((size_t)E_ * 2);
  bf16* wq_b  = (bf16*)alloc((size_t)W_ * 2);
  bf16* wk_b  = (bf16*)alloc((size_t)W_ * 2);
  bf16* wv_b  = (bf16*)alloc((size_t)W_ * 2);
  bf16* wo_b  = (bf16*)alloc((size_t)W_ * 2);
  bf16* Qraw  = (bf16*)alloc((size_t)E_ * 2);
  bf16* Kraw  = (bf16*)alloc((size_t)E_ * 2);
  bf16* Vraw  = (bf16*)alloc((size_t)E_ * 2);
  bf16* Vt    = (bf16*)alloc((size_t)E_ * 2);
  bf16* Oh    = (bf16*)alloc((size_t)E_ * 2);
  float* ct   = (float*)alloc((size_t)L_ * 64 * 4);
  float* st2  = (float*)alloc((size_t)L_ * 64 * 4);

  float* out0     = (float*)d_out;
  float* attn_out = out0 + E_;

  cvt_f32_bf16<<<8192, 256, 0, stream>>>(x_q,  xq_b,  E_);
  cvt_f32_bf16<<<8192, 256, 0, stream>>>(x_kv, xkv_b, E_);
  cvt_f32_bf16<<<4096, 256, 0, stream>>>(w_q, wq_b, W_);
  cvt_f32_bf16<<<4096, 256, 0, stream>>>(w_k, wk_b, W_);
  cvt_f32_bf16<<<4096, 256, 0, stream>>>(w_v, wv_b, W_);
  cvt_f32_bf16<<<4096, 256, 0, stream>>>(w_o, wo_b, W_);
  rope_table<<<L_, 64, 0, stream>>>(ct, st2);

  gemm_bt<1><<<dim3(16, 32), 256, 0, stream>>>(xq_b,  wq_b, Qraw, B_*L_, D_, D_);
  gemm_bt<1><<<dim3(16, 32), 256, 0, stream>>>(xkv_b, wk_b, Kraw, B_*L_, D_, D_);
  gemm_bt<1><<<dim3(16, 32), 256, 0, stream>>>(xkv_b, wv_b, Vraw, B_*L_, D_, D_);

  rope_inplace<<<8192, 256, 0, stream>>>(Qraw, Kraw, ct, st2);
  transpose_v<<<dim3(64, 4, 32), dim3(32, 8), 0, stream>>>(Vraw, Vt);
  zero_upper<<<dim3(2048, 32), 256, 0, stream>>>(attn_out);
  attn_fused<<<dim3(16, 32), 512, 0, stream>>>(Qraw, Kraw, Vt, attn_out, Oh);
  gemm_bt<0><<<dim3(16, 32), 256, 0, stream>>>(Oh, wo_b, out0, B_*L_, D_, D_);
}

// Round 4
// 477.482 us; speedup vs baseline: 2.1905x; 1.0240x over previous
//
#include <hip/hip_runtime.h>
#include <hip/hip_bf16.h>
#include <math.h>

#define B_ 2
#define L_ 2048
#define D_ 2048
#define H_ 16
#define HD_ 128
#define E_ (B_*L_*D_)   // 8388608
#define W_ (D_*D_)      // 4194304

typedef __bf16 bf16;
typedef __bf16 bf16x8 __attribute__((ext_vector_type(8)));
typedef __bf16 bf16x4 __attribute__((ext_vector_type(4)));
typedef float  f32x4  __attribute__((ext_vector_type(4)));

// async global->LDS, 16B per lane; lds ptr must be wave-uniform
#define GLL16(gp_, lp_) __builtin_amdgcn_global_load_lds( \
    (const __attribute__((address_space(1))) void*)(gp_), \
    (__attribute__((address_space(3))) void*)(lp_), 16, 0, 0)

#define BARRIER() do { asm volatile("" ::: "memory"); \
    __builtin_amdgcn_s_barrier(); \
    asm volatile("" ::: "memory"); } while (0)

#define WAITN(N) asm volatile("s_waitcnt vmcnt(" #N ")" ::: "memory")

// ---------------- f32 -> bf16 convert (2 tensors / 4 tensors per launch) ----------------
__global__ void cvt2(const float* __restrict__ s0, const float* __restrict__ s1,
                     bf16* __restrict__ d0, bf16* __restrict__ d1, int n) {
  const float* s = blockIdx.y ? s1 : s0;
  bf16* d = blockIdx.y ? d1 : d0;
  int i = (blockIdx.x * blockDim.x + threadIdx.x) * 4;
  if (i + 3 < n) {
    f32x4 v = *reinterpret_cast<const f32x4*>(s + i);
    bf16x4 o;
    o[0] = (bf16)v[0]; o[1] = (bf16)v[1]; o[2] = (bf16)v[2]; o[3] = (bf16)v[3];
    *reinterpret_cast<bf16x4*>(d + i) = o;
  }
}
__global__ void cvt4(const float* __restrict__ s0, const float* __restrict__ s1,
                     const float* __restrict__ s2, const float* __restrict__ s3,
                     bf16* __restrict__ d0, bf16* __restrict__ d1,
                     bf16* __restrict__ d2, bf16* __restrict__ d3, int n) {
  const float* s; bf16* d;
  switch (blockIdx.y) {
    case 0: s = s0; d = d0; break;
    case 1: s = s1; d = d1; break;
    case 2: s = s2; d = d2; break;
    default: s = s3; d = d3; break;
  }
  int i = (blockIdx.x * blockDim.x + threadIdx.x) * 4;
  if (i + 3 < n) {
    f32x4 v = *reinterpret_cast<const f32x4*>(s + i);
    bf16x4 o;
    o[0] = (bf16)v[0]; o[1] = (bf16)v[1]; o[2] = (bf16)v[2]; o[3] = (bf16)v[3];
    *reinterpret_cast<bf16x4*>(d + i) = o;
  }
}

// ---------------- RoPE cos/sin table: [L][64] ----------------
__global__ void rope_table(float* __restrict__ ct, float* __restrict__ st) {
  int t = blockIdx.x;
  int i = threadIdx.x;
  float inv = powf(10000.0f, -2.0f * (float)i / 128.0f);
  float f = (float)t * inv;
  ct[t * 64 + i] = cosf(f);
  st[t * 64 + i] = sinf(f);
}

// ---------------- in-place RoPE on Q and K ----------------
__global__ void rope_inplace(bf16* __restrict__ Q, bf16* __restrict__ Kt,
                             const float* __restrict__ ct, const float* __restrict__ st) {
  size_t idx = (size_t)blockIdx.x * blockDim.x + threadIdx.x;
  const size_t per = E_ / 8;
  bf16* P = (idx < per) ? Q : Kt;
  size_t li = ((idx < per) ? idx : idx - per) * 8;
  int l   = (int)((li / D_) % L_);
  int col = (int)(li % D_);
  int i0  = (col & 127) >> 1;
  bf16x8 v = *reinterpret_cast<const bf16x8*>(P + li);
  f32x4 c4 = *reinterpret_cast<const f32x4*>(ct + l * 64 + i0);
  f32x4 s4 = *reinterpret_cast<const f32x4*>(st + l * 64 + i0);
  bf16x8 o;
#pragma unroll
  for (int p = 0; p < 4; ++p) {
    float x1 = (float)v[2*p], x2 = (float)v[2*p+1];
    o[2*p]   = (bf16)(x1 * c4[p] - x2 * s4[p]);
    o[2*p+1] = (bf16)(x1 * s4[p] + x2 * c4[p]);
  }
  *reinterpret_cast<bf16x8*>(P + li) = o;
}

// ---------------- V (b,l,h*128+d) -> Vt (b,h,d,l) tiled transpose ----------------
__global__ void transpose_v(const bf16* __restrict__ Vraw, bf16* __restrict__ Vt) {
  __shared__ bf16 tile[32][33];
  int bh = blockIdx.z; int b = bh >> 4, h = bh & 15;
  int l0 = blockIdx.x * 32, d0 = blockIdx.y * 32;
  int tx = threadIdx.x, ty = threadIdx.y;
#pragma unroll
  for (int j = 0; j < 4; ++j) {
    int r = ty + j * 8;
    tile[r][tx] = Vraw[((size_t)b * L_ + l0 + r) * D_ + h * HD_ + d0 + tx];
  }
  __syncthreads();
#pragma unroll
  for (int j = 0; j < 4; ++j) {
    int r = ty + j * 8;
    Vt[((size_t)bh * HD_ + d0 + r) * L_ + l0 + tx] = tile[tx][r];
  }
}

// ---------------- GEMM: C[M,N] = A[M,K] @ Bw[N,K]^T (m97 structure) ----------------
template<int OUT_BF16>
__global__ __launch_bounds__(256, 4) void gemm_bt(const bf16* __restrict__ A,
                                                  const bf16* __restrict__ Bw,
                                                  void* __restrict__ Cout,
                                                  int M, int N, int K) {
  __shared__ bf16 As[128 * 64];
  __shared__ bf16 Bs[128 * 64];
  const int tid = threadIdx.x;
  const int lane = tid & 63;
  const int w = tid >> 6;
  const int l15 = lane & 15, lg = lane >> 4;
  const int m0 = blockIdx.y * 128, n0 = blockIdx.x * 128;
  const int wm = (w >> 1) * 64, wn = (w & 1) * 64;

  int rowS[4], schS[4];
#pragma unroll
  for (int s = 0; s < 4; ++s) {
    int cl = s * 256 + tid;
    rowS[s] = cl >> 3;
    schS[s] = ((cl & 7) ^ ((cl >> 3) & 7)) << 3;
  }

  f32x4 acc[4][4];
#pragma unroll
  for (int m = 0; m < 4; ++m)
#pragma unroll
    for (int n = 0; n < 4; ++n) acc[m][n] = (f32x4){0.f, 0.f, 0.f, 0.f};

  for (int kt = 0; kt < K; kt += 64) {
    __syncthreads();
#pragma unroll
    for (int s = 0; s < 4; ++s) {
      GLL16(A  + (size_t)(m0 + rowS[s]) * K + kt + schS[s], As + s * 2048 + w * 512);
      GLL16(Bw + (size_t)(n0 + rowS[s]) * K + kt + schS[s], Bs + s * 2048 + w * 512);
    }
    __syncthreads();
#pragma unroll
    for (int kk = 0; kk < 64; kk += 32) {
      bf16x8 af[4], bfr[4];
#pragma unroll
      for (int m = 0; m < 4; ++m)
        af[m] = *reinterpret_cast<const bf16x8*>(
            As + (wm + m * 16 + l15) * 64 + ((((kk >> 3) + lg) ^ (l15 & 7)) << 3));
#pragma unroll
      for (int n = 0; n < 4; ++n)
        bfr[n] = *reinterpret_cast<const bf16x8*>(
            Bs + (wn + n * 16 + l15) * 64 + ((((kk >> 3) + lg) ^ (l15 & 7)) << 3));
#pragma unroll
      for (int m = 0; m < 4; ++m)
#pragma unroll
        for (int n = 0; n < 4; ++n)
          acc[m][n] = __builtin_amdgcn_mfma_f32_16x16x32_bf16(af[m], bfr[n], acc[m][n], 0, 0, 0);
    }
  }
#pragma unroll
  for (int m = 0; m < 4; ++m) {
    int orow = m0 + wm + m * 16 + lg * 4;
#pragma unroll
    for (int n = 0; n < 4; ++n) {
      int col = n0 + wn + n * 16 + l15;
#pragma unroll
      for (int r = 0; r < 4; ++r) {
        if (OUT_BF16) ((bf16*)Cout)[(size_t)(orow + r) * N + col] = (bf16)acc[m][n][r];
        else          ((float*)Cout)[(size_t)(orow + r) * N + col] = acc[m][n][r];
      }
    }
  }
}

// ---------------- fused causal attention (zeros folded in, counted vmcnt) ----------------
// grid (16, 32) remapped so co-resident blocks have complementary work.
// Block work-id x: waves 0-3 own tile x, waves 4-7 own tile 31-x; loop runs 32-x groups.
__global__ __launch_bounds__(512, 4) void attn_fused(const bf16* __restrict__ Qb,
                                                     const bf16* __restrict__ Kb,
                                                     const bf16* __restrict__ Vt,
                                                     float* __restrict__ attn,
                                                     bf16* __restrict__ Oh) {
  __shared__ bf16 Klds[2][64 * 128];   // 32 KB
  __shared__ bf16 Vlds[128 * 64];      // 16 KB
  __shared__ bf16 Plds[8][16][72];     // 18 KB

  const int tid = threadIdx.x;
  const int w = tid >> 6, lane = tid & 63;
  const int l15 = lane & 15, lg = lane >> 4;

  // bijective remap: pair (x, bh<16) with (15-x, bh>=16) at distance 256 in dispatch order
  int g = blockIdx.x + 16 * blockIdx.y;
  int x, bh;
  if (g < 256) { x = g & 15;        bh = g >> 4; }
  else { int h2 = g - 256; x = 15 - (h2 & 15); bh = 16 + (h2 >> 4); }
  const int b = bh >> 4, h = bh & 15;

  const int qt = (w < 4) ? x : (31 - x);
  const int q0w = qt * 64 + (w & 3) * 16;
  const int ntW = qt + 1;                   // groups this wave computes
  const int ntB = 32 - x;                   // loop trip count (max over waves)
  const float sc2 = 0.08838834764831845f * 1.44269504088896f;

  const bf16* kb = Kb + ((size_t)b * L_) * D_ + h * HD_;
  const bf16* vb = Vt + (size_t)bh * HD_ * L_;
  float* arow = attn + ((size_t)bh * L_ + q0w) * L_;

  bf16x8 qf[4];
  {
    const bf16* qrow = Qb + ((size_t)b * L_ + q0w + l15) * D_ + h * HD_;
#pragma unroll
    for (int c = 0; c < 4; ++c)
      qf[c] = *reinterpret_cast<const bf16x8*>(qrow + c * 32 + lg * 8);
  }

  const int t1 = 512 + tid;
  const int rK0 = tid >> 4, sK0 = ((tid & 15) ^ (rK0 & 7)) << 3;
  const int rK1 = t1 >> 4,  sK1 = ((t1 & 15) ^ (rK1 & 7)) << 3;
  const int rV0 = tid >> 3, sV0 = ((tid & 7) ^ (rV0 & 7)) << 3;
  const int rV1 = t1 >> 3,  sV1 = ((t1 & 7) ^ (rV1 & 7)) << 3;
  bf16* ldsK0 = &Klds[0][0] + w * 512;
  bf16* ldsK1 = &Klds[0][0] + 4096 + w * 512;
  bf16* ldsV0 = Vlds + w * 512;
  bf16* ldsV1 = Vlds + 4096 + w * 512;

  auto stageK = [&](int gp, int buf) {
    GLL16(kb + (size_t)(gp * 64 + rK0) * D_ + sK0, ldsK0 + buf * 8192);
    GLL16(kb + (size_t)(gp * 64 + rK1) * D_ + sK1, ldsK1 + buf * 8192);
  };
  auto stageV = [&](int gp) {
    GLL16(vb + (size_t)rV0 * L_ + gp * 64 + sV0, ldsV0);
    GLL16(vb + (size_t)rV1 * L_ + gp * 64 + sV1, ldsV1);
  };
  auto qkt = [&](const bf16* kl, f32x4* acc) {
#pragma unroll
    for (int c = 0; c < 4; ++c)
#pragma unroll
      for (int t = 0; t < 4; ++t) {
        bf16x8 kf = *reinterpret_cast<const bf16x8*>(
            kl + (t * 16 + l15) * 128 + ((((c << 2) + lg) ^ (l15 & 7)) << 3));
        acc[t] = __builtin_amdgcn_mfma_f32_16x16x32_bf16(qf[c], kf, acc[t], 0, 0, 0);
      }
  };

  // ================= pass 1: row sums (+ upper-zero writes from idle waves) =================
  float sum[4] = {0.f, 0.f, 0.f, 0.f};
  stageK(0, 0);
  for (int gp = 0; gp < ntB; ++gp) {
    BARRIER();                               // A: prev QK reads done
    const bool hn = (gp + 1 < ntB);
    if (hn) stageK(gp + 1, (gp + 1) & 1);
    // wait K(gp): allowed outstanding = 16*(prev iter zero-stored) + 2*hn
    const bool pz = (gp > 0) && ((gp - 1) >= ntW);
    if (pz) { if (hn) WAITN(18); else WAITN(16); }
    else    { if (hn) WAITN(2);  else WAITN(0);  }
    BARRIER();                               // B: K(gp) visible to all
    if (gp < ntW) {
      f32x4 acc[4] = {(f32x4){0,0,0,0},(f32x4){0,0,0,0},(f32x4){0,0,0,0},(f32x4){0,0,0,0}};
      qkt(&Klds[gp & 1][0], acc);
      if (gp < qt) {
#pragma unroll
        for (int t = 0; t < 4; ++t)
#pragma unroll
          for (int r = 0; r < 4; ++r)
            sum[r] += exp2f(acc[t][r] * sc2);
      } else {
#pragma unroll
        for (int t = 0; t < 4; ++t)
#pragma unroll
          for (int r = 0; r < 4; ++r) {
            int kc = gp * 64 + t * 16 + l15;
            int qr = q0w + lg * 4 + r;
            sum[r] += (kc <= qr) ? exp2f(acc[t][r] * sc2) : 0.f;
          }
      }
    } else {
      // idle group: write this wave's 16 rows x 64 zero cols (16 dword stores)
#pragma unroll
      for (int t = 0; t < 4; ++t)
#pragma unroll
        for (int r = 0; r < 4; ++r)
          arow[(size_t)(lg * 4 + r) * L_ + gp * 64 + t * 16 + l15] = 0.f;
    }
  }
#pragma unroll
  for (int r = 0; r < 4; ++r) {
#pragma unroll
    for (int sh = 1; sh < 16; sh <<= 1)
      sum[r] += __shfl_xor(sum[r], sh, 64);
  }
  float rinv[4];
#pragma unroll
  for (int r = 0; r < 4; ++r) rinv[r] = 1.0f / sum[r];

  // ================= pass 2: write P, accumulate PV =================
  f32x4 oacc[8];
#pragma unroll
  for (int i = 0; i < 8; ++i) oacc[i] = (f32x4){0.f, 0.f, 0.f, 0.f};

  BARRIER();                                 // phase boundary: Klds reusable
  stageK(0, 0);
  for (int gp = 0; gp < ntB; ++gp) {
    BARRIER();                               // A: prev PV reads done -> Vlds reusable
    stageV(gp);
    const bool hn = (gp + 1 < ntB);
    if (hn) stageK(gp + 1, (gp + 1) & 1);
    // wait K(gp): allowed = 16*(prev iter P-stored) + 2 (V(gp)) + 2*hn
    const bool ps = (gp > 0) && ((gp - 1) < ntW);
    if (ps) { if (hn) WAITN(20); else WAITN(18); }
    else    { if (hn) WAITN(4);  else WAITN(2);  }
    BARRIER();                               // B: K(gp) visible to all
    const bool act = gp < ntW;
    float pv[4][4];
    if (act) {
      f32x4 acc[4] = {(f32x4){0,0,0,0},(f32x4){0,0,0,0},(f32x4){0,0,0,0},(f32x4){0,0,0,0}};
      qkt(&Klds[gp & 1][0], acc);
      if (gp < qt) {
#pragma unroll
        for (int t = 0; t < 4; ++t)
#pragma unroll
          for (int r = 0; r < 4; ++r)
            pv[t][r] = exp2f(acc[t][r] * sc2) * rinv[r];
      } else {
#pragma unroll
        for (int t = 0; t < 4; ++t)
#pragma unroll
          for (int r = 0; r < 4; ++r) {
            int kc = gp * 64 + t * 16 + l15;
            int qr = q0w + lg * 4 + r;
            pv[t][r] = (kc <= qr) ? exp2f(acc[t][r] * sc2) * rinv[r] : 0.f;
          }
      }
#pragma unroll
      for (int t = 0; t < 4; ++t)
#pragma unroll
        for (int r = 0; r < 4; ++r)
          Plds[w][lg * 4 + r][t * 16 + l15] = (bf16)pv[t][r];
    }
    // wait V(gp): allowed = 2*hn (K(gp+1)); older P-stores of gp-1 have had a full group to drain
    if (hn) WAITN(2); else WAITN(0);
    if (act) {
#pragma unroll
      for (int t = 0; t < 4; ++t)
#pragma unroll
        for (int r = 0; r < 4; ++r)
          arow[(size_t)(lg * 4 + r) * L_ + gp * 64 + t * 16 + l15] = pv[t][r];
    }
    BARRIER();                               // C: V(gp) visible to all
    if (act) {
      asm volatile("s_waitcnt lgkmcnt(0)" ::: "memory");
      __builtin_amdgcn_sched_barrier(0);
#pragma unroll
      for (int ck = 0; ck < 2; ++ck) {
        bf16x8 pa = *reinterpret_cast<const bf16x8*>(&Plds[w][l15][ck * 32 + lg * 8]);
#pragma unroll
        for (int t8 = 0; t8 < 8; ++t8) {
          bf16x8 vf = *reinterpret_cast<const bf16x8*>(
              Vlds + (t8 * 16 + l15) * 64 + ((((ck << 2) + lg) ^ (l15 & 7)) << 3));
          oacc[t8] = __builtin_amdgcn_mfma_f32_16x16x32_bf16(pa, vf, oacc[t8], 0, 0, 0);
        }
      }
      asm volatile("s_waitcnt lgkmcnt(0)" ::: "memory");
    }
  }

  // tail zeros: cols [ntB*64, 2048) for this wave's 16 rows (vectorized)
  for (int gp2 = ntB; gp2 < 32; ++gp2) {
#pragma unroll
    for (int it = 0; it < 4; ++it)
      *reinterpret_cast<f32x4*>(arow + (size_t)l15 * L_ + gp2 * 64 + lg * 4 + it * 16)
          = (f32x4){0.f, 0.f, 0.f, 0.f};
  }

  bf16* orow = Oh + ((size_t)b * L_ + q0w) * D_ + h * HD_;
#pragma unroll
  for (int t8 = 0; t8 < 8; ++t8)
#pragma unroll
    for (int r = 0; r < 4; ++r)
      orow[(size_t)(lg * 4 + r) * D_ + t8 * 16 + l15] = (bf16)oacc[t8][r];
}

// ---------------- host ----------------
extern "C" void kernel_launch(void* const* d_in, const int* in_sizes, int n_in,
                              void* d_out, int out_size, void* d_ws, size_t ws_size,
                              hipStream_t stream) {
  const float* x_q  = (const float*)d_in[0];
  const float* x_kv = (const float*)d_in[1];
  const float* w_q = (const float*)d_in[3];
  const float* w_k = (const float*)d_in[4];
  const float* w_v = (const float*)d_in[5];
  const float* w_o = (const float*)d_in[6];

  char* p = (char*)d_ws;
  auto alloc = [&](size_t bytes) { char* r = p; p += (bytes + 255) & ~(size_t)255; return r; };
  bf16* xq_b  = (bf16*)alloc((size_t)E_ * 2);
  bf16* xkv_b = (bf16*)alloc((size_t)E_ * 2);
  bf16* wq_b  = (bf16*)alloc((size_t)W_ * 2);
  bf16* wk_b  = (bf16*)alloc((size_t)W_ * 2);
  bf16* wv_b  = (bf16*)alloc((size_t)W_ * 2);
  bf16* wo_b  = (bf16*)alloc((size_t)W_ * 2);
  bf16* Qraw  = (bf16*)alloc((size_t)E_ * 2);
  bf16* Kraw  = (bf16*)alloc((size_t)E_ * 2);
  bf16* Vraw  = (bf16*)alloc((size_t)E_ * 2);
  bf16* Vt    = (bf16*)alloc((size_t)E_ * 2);
  bf16* Oh    = (bf16*)alloc((size_t)E_ * 2);
  float* ct   = (float*)alloc((size_t)L_ * 64 * 4);
  float* st2  = (float*)alloc((size_t)L_ * 64 * 4);

  float* out0     = (float*)d_out;
  float* attn_out = out0 + E_;

  cvt2<<<dim3(8192, 2), 256, 0, stream>>>(x_q, x_kv, xq_b, xkv_b, E_);
  cvt4<<<dim3(4096, 4), 256, 0, stream>>>(w_q, w_k, w_v, w_o, wq_b, wk_b, wv_b, wo_b, W_);
  rope_table<<<L_, 64, 0, stream>>>(ct, st2);

  gemm_bt<1><<<dim3(16, 32), 256, 0, stream>>>(xq_b,  wq_b, Qraw, B_*L_, D_, D_);
  gemm_bt<1><<<dim3(16, 32), 256, 0, stream>>>(xkv_b, wk_b, Kraw, B_*L_, D_, D_);
  gemm_bt<1><<<dim3(16, 32), 256, 0, stream>>>(xkv_b, wv_b, Vraw, B_*L_, D_, D_);

  rope_inplace<<<8192, 256, 0, stream>>>(Qraw, Kraw, ct, st2);
  transpose_v<<<dim3(64, 4, 32), dim3(32, 8), 0, stream>>>(Vraw, Vt);
  attn_fused<<<dim3(16, 32), 512, 0, stream>>>(Qraw, Kraw, Vt, attn_out, Oh);
  gemm_bt<0><<<dim3(16, 32), 256, 0, stream>>>(Oh, wo_b, out0, B_*L_, D_, D_);
}

// Round 5
// 446.188 us; speedup vs baseline: 2.3441x; 1.0701x over previous
//
#include <hip/hip_runtime.h>
#include <hip/hip_bf16.h>
#include <math.h>

#define B_ 2
#define L_ 2048
#define D_ 2048
#define H_ 16
#define HD_ 128
#define E_ (B_*L_*D_)   // 8388608
#define W_ (D_*D_)      // 4194304

typedef __bf16 bf16;
typedef __bf16 bf16x8 __attribute__((ext_vector_type(8)));
typedef __bf16 bf16x4 __attribute__((ext_vector_type(4)));
typedef float  f32x4  __attribute__((ext_vector_type(4)));

// async global->LDS, 16B per lane; lds ptr must be wave-uniform
#define GLL16(gp_, lp_) __builtin_amdgcn_global_load_lds( \
    (const __attribute__((address_space(1))) void*)(gp_), \
    (__attribute__((address_space(3))) void*)(lp_), 16, 0, 0)

#define BARRIER() do { asm volatile("" ::: "memory"); \
    __builtin_amdgcn_s_barrier(); \
    asm volatile("" ::: "memory"); } while (0)

#define WAITN(N) asm volatile("s_waitcnt vmcnt(" #N ")" ::: "memory")

// ---------------- prep: all f32->bf16 converts + rope table, one launch ----------------
__global__ void prep(const float* __restrict__ xq, const float* __restrict__ xkv,
                     const float* __restrict__ wq, const float* __restrict__ wk,
                     const float* __restrict__ wv, const float* __restrict__ wo,
                     bf16* __restrict__ xqb, bf16* __restrict__ xkvb,
                     bf16* __restrict__ wqb, bf16* __restrict__ wkb,
                     bf16* __restrict__ wvb, bf16* __restrict__ wob,
                     float* __restrict__ ct, float* __restrict__ st) {
  int g = blockIdx.x;
  if (g < 16384) {
    const float* s = (g < 8192) ? xq : xkv;
    bf16* d = (g < 8192) ? xqb : xkvb;
    int i = ((g & 8191) * 256 + threadIdx.x) * 4;
    f32x4 v = *reinterpret_cast<const f32x4*>(s + i);
    bf16x4 o; o[0]=(bf16)v[0]; o[1]=(bf16)v[1]; o[2]=(bf16)v[2]; o[3]=(bf16)v[3];
    *reinterpret_cast<bf16x4*>(d + i) = o;
  } else if (g < 32768) {
    int gg = g - 16384;
    int which = gg >> 12;
    const float* s = (which==0)?wq:(which==1)?wk:(which==2)?wv:wo;
    bf16* d = (which==0)?wqb:(which==1)?wkb:(which==2)?wvb:wob;
    int i = ((gg & 4095) * 256 + threadIdx.x) * 4;
    f32x4 v = *reinterpret_cast<const f32x4*>(s + i);
    bf16x4 o; o[0]=(bf16)v[0]; o[1]=(bf16)v[1]; o[2]=(bf16)v[2]; o[3]=(bf16)v[3];
    *reinterpret_cast<bf16x4*>(d + i) = o;
  } else {
    int idx = (g - 32768) * 256 + threadIdx.x;   // < 131072 = 2048*64
    int t = idx >> 6, i = idx & 63;
    float inv = powf(10000.0f, -2.0f * (float)i / 128.0f);
    float f = (float)t * inv;
    ct[t * 64 + i] = cosf(f);
    st[t * 64 + i] = sinf(f);
  }
}

// ---------------- fused QKV GEMM + RoPE epilogue + V-transpose epilogue ----------------
// grid (48, 32): blockIdx.x>>4 selects Q/K/V; 128x128 tile, BK=64, m97 staging.
__global__ __launch_bounds__(256, 4) void gemm_qkv(
    const bf16* __restrict__ xq, const bf16* __restrict__ xkv,
    const bf16* __restrict__ wq, const bf16* __restrict__ wk, const bf16* __restrict__ wv,
    const float* __restrict__ ct, const float* __restrict__ st,
    bf16* __restrict__ Qo, bf16* __restrict__ Ko, bf16* __restrict__ Vt) {
  __shared__ bf16 As[128 * 64];
  __shared__ bf16 Bs[128 * 64];
  const int tid = threadIdx.x;
  const int lane = tid & 63;
  const int w = tid >> 6;
  const int l15 = lane & 15, lg = lane >> 4;
  const int which = blockIdx.x >> 4;            // 0=Q, 1=K, 2=V
  const int n0 = (blockIdx.x & 15) * 128;       // local col within 2048
  const int m0 = blockIdx.y * 128;
  const int wm = (w >> 1) * 64, wn = (w & 1) * 64;
  const bf16* A  = (which == 0) ? xq : xkv;
  const bf16* Wt = (which == 0) ? wq : ((which == 1) ? wk : wv);

  int rowS[4], schS[4];
#pragma unroll
  for (int s = 0; s < 4; ++s) {
    int cl = s * 256 + tid;
    rowS[s] = cl >> 3;
    schS[s] = ((cl & 7) ^ ((cl >> 3) & 7)) << 3;
  }

  f32x4 acc[4][4];
#pragma unroll
  for (int m = 0; m < 4; ++m)
#pragma unroll
    for (int n = 0; n < 4; ++n) acc[m][n] = (f32x4){0.f, 0.f, 0.f, 0.f};

  for (int kt = 0; kt < D_; kt += 64) {
    __syncthreads();
#pragma unroll
    for (int s = 0; s < 4; ++s) {
      GLL16(A  + (size_t)(m0 + rowS[s]) * D_ + kt + schS[s], As + s * 2048 + w * 512);
      GLL16(Wt + (size_t)(n0 + rowS[s]) * D_ + kt + schS[s], Bs + s * 2048 + w * 512);
    }
    __syncthreads();
#pragma unroll
    for (int kk = 0; kk < 64; kk += 32) {
      bf16x8 af[4], bfr[4];
#pragma unroll
      for (int m = 0; m < 4; ++m)
        af[m] = *reinterpret_cast<const bf16x8*>(
            As + (wm + m * 16 + l15) * 64 + ((((kk >> 3) + lg) ^ (l15 & 7)) << 3));
#pragma unroll
      for (int n = 0; n < 4; ++n)
        bfr[n] = *reinterpret_cast<const bf16x8*>(
            Bs + (wn + n * 16 + l15) * 64 + ((((kk >> 3) + lg) ^ (l15 & 7)) << 3));
#pragma unroll
      for (int m = 0; m < 4; ++m)
#pragma unroll
        for (int n = 0; n < 4; ++n)
          acc[m][n] = __builtin_amdgcn_mfma_f32_16x16x32_bf16(af[m], bfr[n], acc[m][n], 0, 0, 0);
    }
  }

  if (which == 2) {
    // V: write directly transposed into Vt[(b*16+h)*128+d][l]
    const int b = m0 >> 11;
    const int l0b = (m0 & 2047) + wm + lg * 4;
#pragma unroll
    for (int m = 0; m < 4; ++m) {
      int l0 = l0b + m * 16;
#pragma unroll
      for (int n = 0; n < 4; ++n) {
        int c = n0 + wn + n * 16 + l15;        // head-major col
        int hd = (b * 16 + (c >> 7)) * 128 + (c & 127);
        bf16x4 o;
        o[0] = (bf16)acc[m][n][0]; o[1] = (bf16)acc[m][n][1];
        o[2] = (bf16)acc[m][n][2]; o[3] = (bf16)acc[m][n][3];
        *reinterpret_cast<bf16x4*>(Vt + (size_t)hd * L_ + l0) = o;
      }
    }
  } else {
    // Q/K: apply RoPE (pair partner lives in lane l15^1), then store
    bf16* Out = which ? Ko : Qo;
    const bool odd = (l15 & 1);
#pragma unroll
    for (int m = 0; m < 4; ++m) {
      int row = m0 + wm + m * 16 + lg * 4;
      int l = row & 2047;
#pragma unroll
      for (int n = 0; n < 4; ++n) {
        int c = n0 + wn + n * 16 + l15;
        int i = (c & 127) >> 1;
#pragma unroll
        for (int r = 0; r < 4; ++r) {
          float own = acc[m][n][r];
          float prt = __shfl_xor(own, 1, 64);
          float cc = ct[(size_t)(l + r) * 64 + i];
          float ss = st[(size_t)(l + r) * 64 + i];
          float res = odd ? (prt * ss + own * cc) : (own * cc - prt * ss);
          Out[(size_t)(row + r) * D_ + c] = (bf16)res;
        }
      }
    }
  }
}

// ---------------- GEMM: C[M,N] = A[M,K] @ Bw[N,K]^T (m97 structure, f32 out) ----------------
__global__ __launch_bounds__(256, 4) void gemm_bt(const bf16* __restrict__ A,
                                                  const bf16* __restrict__ Bw,
                                                  float* __restrict__ Cout,
                                                  int M, int N, int K) {
  __shared__ bf16 As[128 * 64];
  __shared__ bf16 Bs[128 * 64];
  const int tid = threadIdx.x;
  const int lane = tid & 63;
  const int w = tid >> 6;
  const int l15 = lane & 15, lg = lane >> 4;
  const int m0 = blockIdx.y * 128, n0 = blockIdx.x * 128;
  const int wm = (w >> 1) * 64, wn = (w & 1) * 64;

  int rowS[4], schS[4];
#pragma unroll
  for (int s = 0; s < 4; ++s) {
    int cl = s * 256 + tid;
    rowS[s] = cl >> 3;
    schS[s] = ((cl & 7) ^ ((cl >> 3) & 7)) << 3;
  }

  f32x4 acc[4][4];
#pragma unroll
  for (int m = 0; m < 4; ++m)
#pragma unroll
    for (int n = 0; n < 4; ++n) acc[m][n] = (f32x4){0.f, 0.f, 0.f, 0.f};

  for (int kt = 0; kt < K; kt += 64) {
    __syncthreads();
#pragma unroll
    for (int s = 0; s < 4; ++s) {
      GLL16(A  + (size_t)(m0 + rowS[s]) * K + kt + schS[s], As + s * 2048 + w * 512);
      GLL16(Bw + (size_t)(n0 + rowS[s]) * K + kt + schS[s], Bs + s * 2048 + w * 512);
    }
    __syncthreads();
#pragma unroll
    for (int kk = 0; kk < 64; kk += 32) {
      bf16x8 af[4], bfr[4];
#pragma unroll
      for (int m = 0; m < 4; ++m)
        af[m] = *reinterpret_cast<const bf16x8*>(
            As + (wm + m * 16 + l15) * 64 + ((((kk >> 3) + lg) ^ (l15 & 7)) << 3));
#pragma unroll
      for (int n = 0; n < 4; ++n)
        bfr[n] = *reinterpret_cast<const bf16x8*>(
            Bs + (wn + n * 16 + l15) * 64 + ((((kk >> 3) + lg) ^ (l15 & 7)) << 3));
#pragma unroll
      for (int m = 0; m < 4; ++m)
#pragma unroll
        for (int n = 0; n < 4; ++n)
          acc[m][n] = __builtin_amdgcn_mfma_f32_16x16x32_bf16(af[m], bfr[n], acc[m][n], 0, 0, 0);
    }
  }
#pragma unroll
  for (int m = 0; m < 4; ++m) {
    int orow = m0 + wm + m * 16 + lg * 4;
#pragma unroll
    for (int n = 0; n < 4; ++n) {
      int col = n0 + wn + n * 16 + l15;
#pragma unroll
      for (int r = 0; r < 4; ++r)
        Cout[(size_t)(orow + r) * N + col] = acc[m][n][r];
    }
  }
}

// ---------------- fused causal attention (unchanged from round 4) ----------------
__global__ __launch_bounds__(512, 4) void attn_fused(const bf16* __restrict__ Qb,
                                                     const bf16* __restrict__ Kb,
                                                     const bf16* __restrict__ Vt,
                                                     float* __restrict__ attn,
                                                     bf16* __restrict__ Oh) {
  __shared__ bf16 Klds[2][64 * 128];
  __shared__ bf16 Vlds[128 * 64];
  __shared__ bf16 Plds[8][16][72];

  const int tid = threadIdx.x;
  const int w = tid >> 6, lane = tid & 63;
  const int l15 = lane & 15, lg = lane >> 4;

  int g = blockIdx.x + 16 * blockIdx.y;
  int x, bh;
  if (g < 256) { x = g & 15;        bh = g >> 4; }
  else { int h2 = g - 256; x = 15 - (h2 & 15); bh = 16 + (h2 >> 4); }
  const int b = bh >> 4, h = bh & 15;

  const int qt = (w < 4) ? x : (31 - x);
  const int q0w = qt * 64 + (w & 3) * 16;
  const int ntW = qt + 1;
  const int ntB = 32 - x;
  const float sc2 = 0.08838834764831845f * 1.44269504088896f;

  const bf16* kb = Kb + ((size_t)b * L_) * D_ + h * HD_;
  const bf16* vb = Vt + (size_t)bh * HD_ * L_;
  float* arow = attn + ((size_t)bh * L_ + q0w) * L_;

  bf16x8 qf[4];
  {
    const bf16* qrow = Qb + ((size_t)b * L_ + q0w + l15) * D_ + h * HD_;
#pragma unroll
    for (int c = 0; c < 4; ++c)
      qf[c] = *reinterpret_cast<const bf16x8*>(qrow + c * 32 + lg * 8);
  }

  const int t1 = 512 + tid;
  const int rK0 = tid >> 4, sK0 = ((tid & 15) ^ (rK0 & 7)) << 3;
  const int rK1 = t1 >> 4,  sK1 = ((t1 & 15) ^ (rK1 & 7)) << 3;
  const int rV0 = tid >> 3, sV0 = ((tid & 7) ^ (rV0 & 7)) << 3;
  const int rV1 = t1 >> 3,  sV1 = ((t1 & 7) ^ (rV1 & 7)) << 3;
  bf16* ldsK0 = &Klds[0][0] + w * 512;
  bf16* ldsK1 = &Klds[0][0] + 4096 + w * 512;
  bf16* ldsV0 = Vlds + w * 512;
  bf16* ldsV1 = Vlds + 4096 + w * 512;

  auto stageK = [&](int gp, int buf) {
    GLL16(kb + (size_t)(gp * 64 + rK0) * D_ + sK0, ldsK0 + buf * 8192);
    GLL16(kb + (size_t)(gp * 64 + rK1) * D_ + sK1, ldsK1 + buf * 8192);
  };
  auto stageV = [&](int gp) {
    GLL16(vb + (size_t)rV0 * L_ + gp * 64 + sV0, ldsV0);
    GLL16(vb + (size_t)rV1 * L_ + gp * 64 + sV1, ldsV1);
  };
  auto qkt = [&](const bf16* kl, f32x4* acc) {
#pragma unroll
    for (int c = 0; c < 4; ++c)
#pragma unroll
      for (int t = 0; t < 4; ++t) {
        bf16x8 kf = *reinterpret_cast<const bf16x8*>(
            kl + (t * 16 + l15) * 128 + ((((c << 2) + lg) ^ (l15 & 7)) << 3));
        acc[t] = __builtin_amdgcn_mfma_f32_16x16x32_bf16(qf[c], kf, acc[t], 0, 0, 0);
      }
  };

  // ---- pass 1 ----
  float sum[4] = {0.f, 0.f, 0.f, 0.f};
  stageK(0, 0);
  for (int gp = 0; gp < ntB; ++gp) {
    BARRIER();
    const bool hn = (gp + 1 < ntB);
    if (hn) stageK(gp + 1, (gp + 1) & 1);
    const bool pz = (gp > 0) && ((gp - 1) >= ntW);
    if (pz) { if (hn) WAITN(18); else WAITN(16); }
    else    { if (hn) WAITN(2);  else WAITN(0);  }
    BARRIER();
    if (gp < ntW) {
      f32x4 acc[4] = {(f32x4){0,0,0,0},(f32x4){0,0,0,0},(f32x4){0,0,0,0},(f32x4){0,0,0,0}};
      qkt(&Klds[gp & 1][0], acc);
      if (gp < qt) {
#pragma unroll
        for (int t = 0; t < 4; ++t)
#pragma unroll
          for (int r = 0; r < 4; ++r)
            sum[r] += exp2f(acc[t][r] * sc2);
      } else {
#pragma unroll
        for (int t = 0; t < 4; ++t)
#pragma unroll
          for (int r = 0; r < 4; ++r) {
            int kc = gp * 64 + t * 16 + l15;
            int qr = q0w + lg * 4 + r;
            sum[r] += (kc <= qr) ? exp2f(acc[t][r] * sc2) : 0.f;
          }
      }
    } else {
#pragma unroll
      for (int t = 0; t < 4; ++t)
#pragma unroll
        for (int r = 0; r < 4; ++r)
          arow[(size_t)(lg * 4 + r) * L_ + gp * 64 + t * 16 + l15] = 0.f;
    }
  }
#pragma unroll
  for (int r = 0; r < 4; ++r) {
#pragma unroll
    for (int sh = 1; sh < 16; sh <<= 1)
      sum[r] += __shfl_xor(sum[r], sh, 64);
  }
  float rinv[4];
#pragma unroll
  for (int r = 0; r < 4; ++r) rinv[r] = 1.0f / sum[r];

  // ---- pass 2 ----
  f32x4 oacc[8];
#pragma unroll
  for (int i = 0; i < 8; ++i) oacc[i] = (f32x4){0.f, 0.f, 0.f, 0.f};

  BARRIER();
  stageK(0, 0);
  for (int gp = 0; gp < ntB; ++gp) {
    BARRIER();
    stageV(gp);
    const bool hn = (gp + 1 < ntB);
    if (hn) stageK(gp + 1, (gp + 1) & 1);
    const bool ps = (gp > 0) && ((gp - 1) < ntW);
    if (ps) { if (hn) WAITN(20); else WAITN(18); }
    else    { if (hn) WAITN(4);  else WAITN(2);  }
    BARRIER();
    const bool act = gp < ntW;
    float pv[4][4];
    if (act) {
      f32x4 acc[4] = {(f32x4){0,0,0,0},(f32x4){0,0,0,0},(f32x4){0,0,0,0},(f32x4){0,0,0,0}};
      qkt(&Klds[gp & 1][0], acc);
      if (gp < qt) {
#pragma unroll
        for (int t = 0; t < 4; ++t)
#pragma unroll
          for (int r = 0; r < 4; ++r)
            pv[t][r] = exp2f(acc[t][r] * sc2) * rinv[r];
      } else {
#pragma unroll
        for (int t = 0; t < 4; ++t)
#pragma unroll
          for (int r = 0; r < 4; ++r) {
            int kc = gp * 64 + t * 16 + l15;
            int qr = q0w + lg * 4 + r;
            pv[t][r] = (kc <= qr) ? exp2f(acc[t][r] * sc2) * rinv[r] : 0.f;
          }
      }
#pragma unroll
      for (int t = 0; t < 4; ++t)
#pragma unroll
        for (int r = 0; r < 4; ++r)
          Plds[w][lg * 4 + r][t * 16 + l15] = (bf16)pv[t][r];
    }
    if (hn) WAITN(2); else WAITN(0);
    if (act) {
#pragma unroll
      for (int t = 0; t < 4; ++t)
#pragma unroll
        for (int r = 0; r < 4; ++r)
          arow[(size_t)(lg * 4 + r) * L_ + gp * 64 + t * 16 + l15] = pv[t][r];
    }
    BARRIER();
    if (act) {
      asm volatile("s_waitcnt lgkmcnt(0)" ::: "memory");
      __builtin_amdgcn_sched_barrier(0);
#pragma unroll
      for (int ck = 0; ck < 2; ++ck) {
        bf16x8 pa = *reinterpret_cast<const bf16x8*>(&Plds[w][l15][ck * 32 + lg * 8]);
#pragma unroll
        for (int t8 = 0; t8 < 8; ++t8) {
          bf16x8 vf = *reinterpret_cast<const bf16x8*>(
              Vlds + (t8 * 16 + l15) * 64 + ((((ck << 2) + lg) ^ (l15 & 7)) << 3));
          oacc[t8] = __builtin_amdgcn_mfma_f32_16x16x32_bf16(pa, vf, oacc[t8], 0, 0, 0);
        }
      }
      asm volatile("s_waitcnt lgkmcnt(0)" ::: "memory");
    }
  }

  for (int gp2 = ntB; gp2 < 32; ++gp2) {
#pragma unroll
    for (int it = 0; it < 4; ++it)
      *reinterpret_cast<f32x4*>(arow + (size_t)l15 * L_ + gp2 * 64 + lg * 4 + it * 16)
          = (f32x4){0.f, 0.f, 0.f, 0.f};
  }

  bf16* orow = Oh + ((size_t)b * L_ + q0w) * D_ + h * HD_;
#pragma unroll
  for (int t8 = 0; t8 < 8; ++t8)
#pragma unroll
    for (int r = 0; r < 4; ++r)
      orow[(size_t)(lg * 4 + r) * D_ + t8 * 16 + l15] = (bf16)oacc[t8][r];
}

// ---------------- host ----------------
extern "C" void kernel_launch(void* const* d_in, const int* in_sizes, int n_in,
                              void* d_out, int out_size, void* d_ws, size_t ws_size,
                              hipStream_t stream) {
  const float* x_q  = (const float*)d_in[0];
  const float* x_kv = (const float*)d_in[1];
  const float* w_q = (const float*)d_in[3];
  const float* w_k = (const float*)d_in[4];
  const float* w_v = (const float*)d_in[5];
  const float* w_o = (const float*)d_in[6];

  char* p = (char*)d_ws;
  auto alloc = [&](size_t bytes) { char* r = p; p += (bytes + 255) & ~(size_t)255; return r; };
  bf16* xq_b  = (bf16*)alloc((size_t)E_ * 2);
  bf16* xkv_b = (bf16*)alloc((size_t)E_ * 2);
  bf16* wq_b  = (bf16*)alloc((size_t)W_ * 2);
  bf16* wk_b  = (bf16*)alloc((size_t)W_ * 2);
  bf16* wv_b  = (bf16*)alloc((size_t)W_ * 2);
  bf16* wo_b  = (bf16*)alloc((size_t)W_ * 2);
  bf16* Qraw  = (bf16*)alloc((size_t)E_ * 2);
  bf16* Kraw  = (bf16*)alloc((size_t)E_ * 2);
  bf16* Vt    = (bf16*)alloc((size_t)E_ * 2);
  bf16* Oh    = (bf16*)alloc((size_t)E_ * 2);
  float* ct   = (float*)alloc((size_t)L_ * 64 * 4);
  float* st2  = (float*)alloc((size_t)L_ * 64 * 4);

  float* out0     = (float*)d_out;
  float* attn_out = out0 + E_;

  prep<<<33280, 256, 0, stream>>>(x_q, x_kv, w_q, w_k, w_v, w_o,
                                  xq_b, xkv_b, wq_b, wk_b, wv_b, wo_b, ct, st2);
  gemm_qkv<<<dim3(48, 32), 256, 0, stream>>>(xq_b, xkv_b, wq_b, wk_b, wv_b,
                                             ct, st2, Qraw, Kraw, Vt);
  attn_fused<<<dim3(16, 32), 512, 0, stream>>>(Qraw, Kraw, Vt, attn_out, Oh);
  gemm_bt<<<dim3(16, 32), 256, 0, stream>>>(Oh, wo_b, out0, B_*L_, D_, D_);
}

// Round 6
// 394.434 us; speedup vs baseline: 2.6517x; 1.1312x over previous
//
#include <hip/hip_runtime.h>
#include <hip/hip_bf16.h>
#include <math.h>

#define B_ 2
#define L_ 2048
#define D_ 2048
#define H_ 16
#define HD_ 128
#define E_ (B_*L_*D_)   // 8388608
#define W_ (D_*D_)      // 4194304

typedef __bf16 bf16;
typedef __bf16 bf16x8 __attribute__((ext_vector_type(8)));
typedef __bf16 bf16x4 __attribute__((ext_vector_type(4)));
typedef float  f32x4  __attribute__((ext_vector_type(4)));

// async global->LDS, 16B per lane; lds ptr must be wave-uniform
#define GLL16(gp_, lp_) __builtin_amdgcn_global_load_lds( \
    (const __attribute__((address_space(1))) void*)(gp_), \
    (__attribute__((address_space(3))) void*)(lp_), 16, 0, 0)

#define BARRIER() do { asm volatile("" ::: "memory"); \
    __builtin_amdgcn_s_barrier(); \
    asm volatile("" ::: "memory"); } while (0)

#define WAITN(N) asm volatile("s_waitcnt vmcnt(" #N ")" ::: "memory")

// ---------------- prep: all f32->bf16 converts + rope table, one launch ----------------
__global__ void prep(const float* __restrict__ xq, const float* __restrict__ xkv,
                     const float* __restrict__ wq, const float* __restrict__ wk,
                     const float* __restrict__ wv, const float* __restrict__ wo,
                     bf16* __restrict__ xqb, bf16* __restrict__ xkvb,
                     bf16* __restrict__ wqb, bf16* __restrict__ wkb,
                     bf16* __restrict__ wvb, bf16* __restrict__ wob,
                     float* __restrict__ ct, float* __restrict__ st) {
  int g = blockIdx.x;
  if (g < 16384) {
    const float* s = (g < 8192) ? xq : xkv;
    bf16* d = (g < 8192) ? xqb : xkvb;
    int i = ((g & 8191) * 256 + threadIdx.x) * 4;
    f32x4 v = *reinterpret_cast<const f32x4*>(s + i);
    bf16x4 o; o[0]=(bf16)v[0]; o[1]=(bf16)v[1]; o[2]=(bf16)v[2]; o[3]=(bf16)v[3];
    *reinterpret_cast<bf16x4*>(d + i) = o;
  } else if (g < 32768) {
    int gg = g - 16384;
    int which = gg >> 12;
    const float* s = (which==0)?wq:(which==1)?wk:(which==2)?wv:wo;
    bf16* d = (which==0)?wqb:(which==1)?wkb:(which==2)?wvb:wob;
    int i = ((gg & 4095) * 256 + threadIdx.x) * 4;
    f32x4 v = *reinterpret_cast<const f32x4*>(s + i);
    bf16x4 o; o[0]=(bf16)v[0]; o[1]=(bf16)v[1]; o[2]=(bf16)v[2]; o[3]=(bf16)v[3];
    *reinterpret_cast<bf16x4*>(d + i) = o;
  } else {
    int idx = (g - 32768) * 256 + threadIdx.x;   // < 131072 = 2048*64
    int t = idx >> 6, i = idx & 63;
    float inv = powf(10000.0f, -2.0f * (float)i / 128.0f);
    float f = (float)t * inv;
    ct[t * 64 + i] = cosf(f);
    st[t * 64 + i] = sinf(f);
  }
}

// ---------------- fused QKV GEMM + RoPE epilogue + V-transpose epilogue ----------------
__global__ __launch_bounds__(256, 4) void gemm_qkv(
    const bf16* __restrict__ xq, const bf16* __restrict__ xkv,
    const bf16* __restrict__ wq, const bf16* __restrict__ wk, const bf16* __restrict__ wv,
    const float* __restrict__ ct, const float* __restrict__ st,
    bf16* __restrict__ Qo, bf16* __restrict__ Ko, bf16* __restrict__ Vt) {
  __shared__ bf16 As[128 * 64];
  __shared__ bf16 Bs[128 * 64];
  const int tid = threadIdx.x;
  const int lane = tid & 63;
  const int w = tid >> 6;
  const int l15 = lane & 15, lg = lane >> 4;
  const int which = blockIdx.x >> 4;            // 0=Q, 1=K, 2=V
  const int n0 = (blockIdx.x & 15) * 128;
  const int m0 = blockIdx.y * 128;
  const int wm = (w >> 1) * 64, wn = (w & 1) * 64;
  const bf16* A  = (which == 0) ? xq : xkv;
  const bf16* Wt = (which == 0) ? wq : ((which == 1) ? wk : wv);

  int rowS[4], schS[4];
#pragma unroll
  for (int s = 0; s < 4; ++s) {
    int cl = s * 256 + tid;
    rowS[s] = cl >> 3;
    schS[s] = ((cl & 7) ^ ((cl >> 3) & 7)) << 3;
  }

  f32x4 acc[4][4];
#pragma unroll
  for (int m = 0; m < 4; ++m)
#pragma unroll
    for (int n = 0; n < 4; ++n) acc[m][n] = (f32x4){0.f, 0.f, 0.f, 0.f};

  for (int kt = 0; kt < D_; kt += 64) {
    __syncthreads();
#pragma unroll
    for (int s = 0; s < 4; ++s) {
      GLL16(A  + (size_t)(m0 + rowS[s]) * D_ + kt + schS[s], As + s * 2048 + w * 512);
      GLL16(Wt + (size_t)(n0 + rowS[s]) * D_ + kt + schS[s], Bs + s * 2048 + w * 512);
    }
    __syncthreads();
#pragma unroll
    for (int kk = 0; kk < 64; kk += 32) {
      bf16x8 af[4], bfr[4];
#pragma unroll
      for (int m = 0; m < 4; ++m)
        af[m] = *reinterpret_cast<const bf16x8*>(
            As + (wm + m * 16 + l15) * 64 + ((((kk >> 3) + lg) ^ (l15 & 7)) << 3));
#pragma unroll
      for (int n = 0; n < 4; ++n)
        bfr[n] = *reinterpret_cast<const bf16x8*>(
            Bs + (wn + n * 16 + l15) * 64 + ((((kk >> 3) + lg) ^ (l15 & 7)) << 3));
#pragma unroll
      for (int m = 0; m < 4; ++m)
#pragma unroll
        for (int n = 0; n < 4; ++n)
          acc[m][n] = __builtin_amdgcn_mfma_f32_16x16x32_bf16(af[m], bfr[n], acc[m][n], 0, 0, 0);
    }
  }

  if (which == 2) {
    const int b = m0 >> 11;
    const int l0b = (m0 & 2047) + wm + lg * 4;
#pragma unroll
    for (int m = 0; m < 4; ++m) {
      int l0 = l0b + m * 16;
#pragma unroll
      for (int n = 0; n < 4; ++n) {
        int c = n0 + wn + n * 16 + l15;
        int hd = (b * 16 + (c >> 7)) * 128 + (c & 127);
        bf16x4 o;
        o[0] = (bf16)acc[m][n][0]; o[1] = (bf16)acc[m][n][1];
        o[2] = (bf16)acc[m][n][2]; o[3] = (bf16)acc[m][n][3];
        *reinterpret_cast<bf16x4*>(Vt + (size_t)hd * L_ + l0) = o;
      }
    }
  } else {
    bf16* Out = which ? Ko : Qo;
    const bool odd = (l15 & 1);
#pragma unroll
    for (int m = 0; m < 4; ++m) {
      int row = m0 + wm + m * 16 + lg * 4;
      int l = row & 2047;
#pragma unroll
      for (int n = 0; n < 4; ++n) {
        int c = n0 + wn + n * 16 + l15;
        int i = (c & 127) >> 1;
#pragma unroll
        for (int r = 0; r < 4; ++r) {
          float own = acc[m][n][r];
          float prt = __shfl_xor(own, 1, 64);
          float cc = ct[(size_t)(l + r) * 64 + i];
          float ss = st[(size_t)(l + r) * 64 + i];
          float res = odd ? (prt * ss + own * cc) : (own * cc - prt * ss);
          Out[(size_t)(row + r) * D_ + c] = (bf16)res;
        }
      }
    }
  }
}

// ---------------- GEMM: C[M,N] = A[M,K] @ Bw[N,K]^T (m97 structure, f32 out) ----------------
__global__ __launch_bounds__(256, 4) void gemm_bt(const bf16* __restrict__ A,
                                                  const bf16* __restrict__ Bw,
                                                  float* __restrict__ Cout,
                                                  int M, int N, int K) {
  __shared__ bf16 As[128 * 64];
  __shared__ bf16 Bs[128 * 64];
  const int tid = threadIdx.x;
  const int lane = tid & 63;
  const int w = tid >> 6;
  const int l15 = lane & 15, lg = lane >> 4;
  const int m0 = blockIdx.y * 128, n0 = blockIdx.x * 128;
  const int wm = (w >> 1) * 64, wn = (w & 1) * 64;

  int rowS[4], schS[4];
#pragma unroll
  for (int s = 0; s < 4; ++s) {
    int cl = s * 256 + tid;
    rowS[s] = cl >> 3;
    schS[s] = ((cl & 7) ^ ((cl >> 3) & 7)) << 3;
  }

  f32x4 acc[4][4];
#pragma unroll
  for (int m = 0; m < 4; ++m)
#pragma unroll
    for (int n = 0; n < 4; ++n) acc[m][n] = (f32x4){0.f, 0.f, 0.f, 0.f};

  for (int kt = 0; kt < K; kt += 64) {
    __syncthreads();
#pragma unroll
    for (int s = 0; s < 4; ++s) {
      GLL16(A  + (size_t)(m0 + rowS[s]) * K + kt + schS[s], As + s * 2048 + w * 512);
      GLL16(Bw + (size_t)(n0 + rowS[s]) * K + kt + schS[s], Bs + s * 2048 + w * 512);
    }
    __syncthreads();
#pragma unroll
    for (int kk = 0; kk < 64; kk += 32) {
      bf16x8 af[4], bfr[4];
#pragma unroll
      for (int m = 0; m < 4; ++m)
        af[m] = *reinterpret_cast<const bf16x8*>(
            As + (wm + m * 16 + l15) * 64 + ((((kk >> 3) + lg) ^ (l15 & 7)) << 3));
#pragma unroll
      for (int n = 0; n < 4; ++n)
        bfr[n] = *reinterpret_cast<const bf16x8*>(
            Bs + (wn + n * 16 + l15) * 64 + ((((kk >> 3) + lg) ^ (l15 & 7)) << 3));
#pragma unroll
      for (int m = 0; m < 4; ++m)
#pragma unroll
        for (int n = 0; n < 4; ++n)
          acc[m][n] = __builtin_amdgcn_mfma_f32_16x16x32_bf16(af[m], bfr[n], acc[m][n], 0, 0, 0);
    }
  }
#pragma unroll
  for (int m = 0; m < 4; ++m) {
    int orow = m0 + wm + m * 16 + lg * 4;
#pragma unroll
    for (int n = 0; n < 4; ++n) {
      int col = n0 + wn + n * 16 + l15;
#pragma unroll
      for (int r = 0; r < 4; ++r)
        Cout[(size_t)(orow + r) * N + col] = acc[m][n][r];
    }
  }
}

// ---------------- fused causal attention: 4 waves x 32 q-rows, 512 paired blocks ----------------
// Block covers one 128-row q-tile t. Remap pairs tile t with 15-t on the same CU
// (2 blocks/CU, LDS 66KB) -> uniform 34 compute-iters per CU.
__global__ __launch_bounds__(256, 2) void attn_fused(const bf16* __restrict__ Qb,
                                                     const bf16* __restrict__ Kb,
                                                     const bf16* __restrict__ Vt,
                                                     float* __restrict__ attn,
                                                     bf16* __restrict__ Oh) {
  __shared__ bf16 Klds[2][64 * 128];   // 32 KB
  __shared__ bf16 Vlds[128 * 64];      // 16 KB
  __shared__ bf16 Plds[4][32][72];     // 18 KB

  const int tid = threadIdx.x;
  const int w = tid >> 6, lane = tid & 63;
  const int l15 = lane & 15, lg = lane >> 4;

  // pair (tile, bh<16) with (15-tile, bh>=16) at dispatch distance 256
  int g = blockIdx.x + 16 * blockIdx.y;
  int tq, bh;
  if (g < 256) { tq = g & 15;  bh = g >> 4; }
  else { int h2 = g - 256; tq = 15 - (h2 & 15); bh = 16 + (h2 >> 4); }
  const int b = bh >> 4, h = bh & 15;

  const int q0w = tq * 128 + w * 32;        // wave's first q row
  const int ntW = (q0w >> 6) + 1;           // groups this wave computes
  const int ntB = 2 * tq + 2;               // block loop trip count
  const float sc2 = 0.08838834764831845f * 1.44269504088896f;

  const bf16* kb = Kb + ((size_t)b * L_) * D_ + h * HD_;
  const bf16* vb = Vt + (size_t)bh * HD_ * L_;
  float* arow = attn + ((size_t)bh * L_ + q0w) * L_;

  bf16x8 qf[2][4];
#pragma unroll
  for (int qc = 0; qc < 2; ++qc) {
    const bf16* qrow = Qb + ((size_t)b * L_ + q0w + qc * 16 + l15) * D_ + h * HD_;
#pragma unroll
    for (int c = 0; c < 4; ++c)
      qf[qc][c] = *reinterpret_cast<const bf16x8*>(qrow + c * 32 + lg * 8);
  }

  // staging lane constants: 4 calls each (256 threads)
  int rK[4], sK[4], rV[4], sV[4];
#pragma unroll
  for (int s = 0; s < 4; ++s) {
    int ck = s * 256 + tid;
    rK[s] = ck >> 4; sK[s] = ((ck & 15) ^ (rK[s] & 7)) << 3;
    rV[s] = ck >> 3; sV[s] = ((ck & 7) ^ (rV[s] & 7)) << 3;
  }

  auto stageK = [&](int gp, int buf) {
#pragma unroll
    for (int s = 0; s < 4; ++s)
      GLL16(kb + (size_t)(gp * 64 + rK[s]) * D_ + sK[s],
            &Klds[0][0] + buf * 8192 + s * 2048 + w * 512);
  };
  auto stageV = [&](int gp) {
#pragma unroll
    for (int s = 0; s < 4; ++s)
      GLL16(vb + (size_t)rV[s] * L_ + gp * 64 + sV[s],
            Vlds + s * 2048 + w * 512);
  };
  // QK^T for both 16-row chunks; K-fragment reused across chunks
  auto qkt = [&](const bf16* kl, f32x4 acc[2][4]) {
#pragma unroll
    for (int c = 0; c < 4; ++c)
#pragma unroll
      for (int t = 0; t < 4; ++t) {
        bf16x8 kf = *reinterpret_cast<const bf16x8*>(
            kl + (t * 16 + l15) * 128 + ((((c << 2) + lg) ^ (l15 & 7)) << 3));
#pragma unroll
        for (int qc = 0; qc < 2; ++qc)
          acc[qc][t] = __builtin_amdgcn_mfma_f32_16x16x32_bf16(qf[qc][c], kf, acc[qc][t], 0, 0, 0);
      }
  };
  auto zstore32 = [&](int gp) {
#pragma unroll
    for (int qc = 0; qc < 2; ++qc)
#pragma unroll
      for (int t = 0; t < 4; ++t)
#pragma unroll
        for (int r = 0; r < 4; ++r)
          arow[(size_t)(qc * 16 + lg * 4 + r) * L_ + gp * 64 + t * 16 + l15] = 0.f;
  };

  // ================= pass 1: row sums =================
  float sum[2][4] = {{0.f,0.f,0.f,0.f},{0.f,0.f,0.f,0.f}};
  stageK(0, 0);
  for (int gp = 0; gp < ntB; ++gp) {
    BARRIER();                               // A: prev qkt reads done
    const bool hn = (gp + 1 < ntB);
    if (hn) { stageK(gp + 1, (gp + 1) & 1); WAITN(4); }
    else    { WAITN(0); }
    BARRIER();                               // B: K(gp) visible
    if (gp < ntW) {
      f32x4 acc[2][4];
#pragma unroll
      for (int qc = 0; qc < 2; ++qc)
#pragma unroll
        for (int t = 0; t < 4; ++t) acc[qc][t] = (f32x4){0.f,0.f,0.f,0.f};
      qkt(&Klds[gp & 1][0], acc);
      if (gp < ntW - 1) {
#pragma unroll
        for (int qc = 0; qc < 2; ++qc)
#pragma unroll
          for (int t = 0; t < 4; ++t)
#pragma unroll
            for (int r = 0; r < 4; ++r)
              sum[qc][r] += exp2f(acc[qc][t][r] * sc2);
      } else {
#pragma unroll
        for (int qc = 0; qc < 2; ++qc)
#pragma unroll
          for (int t = 0; t < 4; ++t)
#pragma unroll
            for (int r = 0; r < 4; ++r) {
              int kc = gp * 64 + t * 16 + l15;
              int qr = q0w + qc * 16 + lg * 4 + r;
              sum[qc][r] += (kc <= qr) ? exp2f(acc[qc][t][r] * sc2) : 0.f;
            }
      }
    } else {
      zstore32(gp);
    }
  }
  float rinv[2][4];
#pragma unroll
  for (int qc = 0; qc < 2; ++qc)
#pragma unroll
    for (int r = 0; r < 4; ++r) {
      float s = sum[qc][r];
#pragma unroll
      for (int sh = 1; sh < 16; sh <<= 1)
        s += __shfl_xor(s, sh, 64);
      rinv[qc][r] = 1.0f / s;
    }

  // ================= pass 2: write P, accumulate PV =================
  f32x4 oacc[2][8];
#pragma unroll
  for (int qc = 0; qc < 2; ++qc)
#pragma unroll
    for (int i = 0; i < 8; ++i) oacc[qc][i] = (f32x4){0.f, 0.f, 0.f, 0.f};

  BARRIER();                                 // pass1 reads done; Klds reusable
  stageK(0, 0);
  for (int gp = 0; gp < ntB; ++gp) {
    BARRIER();                               // A: prev PV reads done -> Vlds reusable
    stageV(gp);
    const bool hn = (gp + 1 < ntB);
    if (hn) stageK(gp + 1, (gp + 1) & 1);
    // wait K(gp): younger = prev-iter stores(32) + V(gp)(4) + K(gp+1)(4*hn)
    if (gp == 0) { WAITN(8); }
    else if (hn) { WAITN(40); }
    else         { WAITN(36); }
    BARRIER();                               // B: K(gp) visible
    const bool act = gp < ntW;
    float pv[2][4][4];
    if (act) {
      f32x4 acc[2][4];
#pragma unroll
      for (int qc = 0; qc < 2; ++qc)
#pragma unroll
        for (int t = 0; t < 4; ++t) acc[qc][t] = (f32x4){0.f,0.f,0.f,0.f};
      qkt(&Klds[gp & 1][0], acc);
      if (gp < ntW - 1) {
#pragma unroll
        for (int qc = 0; qc < 2; ++qc)
#pragma unroll
          for (int t = 0; t < 4; ++t)
#pragma unroll
            for (int r = 0; r < 4; ++r)
              pv[qc][t][r] = exp2f(acc[qc][t][r] * sc2) * rinv[qc][r];
      } else {
#pragma unroll
        for (int qc = 0; qc < 2; ++qc)
#pragma unroll
          for (int t = 0; t < 4; ++t)
#pragma unroll
            for (int r = 0; r < 4; ++r) {
              int kc = gp * 64 + t * 16 + l15;
              int qr = q0w + qc * 16 + lg * 4 + r;
              pv[qc][t][r] = (kc <= qr) ? exp2f(acc[qc][t][r] * sc2) * rinv[qc][r] : 0.f;
            }
      }
#pragma unroll
      for (int qc = 0; qc < 2; ++qc)
#pragma unroll
        for (int t = 0; t < 4; ++t)
#pragma unroll
          for (int r = 0; r < 4; ++r)
            Plds[w][qc * 16 + lg * 4 + r][t * 16 + l15] = (bf16)pv[qc][t][r];
    }
    // wait V(gp): younger = K(gp+1)(4*hn)
    if (hn) WAITN(4); else WAITN(0);
    if (act) {
#pragma unroll
      for (int qc = 0; qc < 2; ++qc)
#pragma unroll
        for (int t = 0; t < 4; ++t)
#pragma unroll
          for (int r = 0; r < 4; ++r)
            arow[(size_t)(qc * 16 + lg * 4 + r) * L_ + gp * 64 + t * 16 + l15] = pv[qc][t][r];
    } else {
      zstore32(gp);
    }
    BARRIER();                               // C: V(gp) visible
    if (act) {
      asm volatile("s_waitcnt lgkmcnt(0)" ::: "memory");
      __builtin_amdgcn_sched_barrier(0);
      bf16x8 pa[2][2];
#pragma unroll
      for (int qc = 0; qc < 2; ++qc)
#pragma unroll
        for (int ck = 0; ck < 2; ++ck)
          pa[qc][ck] = *reinterpret_cast<const bf16x8*>(&Plds[w][qc * 16 + l15][ck * 32 + lg * 8]);
#pragma unroll
      for (int ck = 0; ck < 2; ++ck)
#pragma unroll
        for (int t8 = 0; t8 < 8; ++t8) {
          bf16x8 vf = *reinterpret_cast<const bf16x8*>(
              Vlds + (t8 * 16 + l15) * 64 + ((((ck << 2) + lg) ^ (l15 & 7)) << 3));
#pragma unroll
          for (int qc = 0; qc < 2; ++qc)
            oacc[qc][t8] = __builtin_amdgcn_mfma_f32_16x16x32_bf16(pa[qc][ck], vf, oacc[qc][t8], 0, 0, 0);
        }
      asm volatile("s_waitcnt lgkmcnt(0)" ::: "memory");
    }
  }

  // tail zeros: cols [ntB*64, 2048) for this wave's 32 rows
  for (int gp2 = ntB; gp2 < 32; ++gp2) {
#pragma unroll
    for (int i = 0; i < 8; ++i)
      *reinterpret_cast<f32x4*>(arow + (size_t)(i * 4 + lg) * L_ + gp2 * 64 + l15 * 4)
          = (f32x4){0.f, 0.f, 0.f, 0.f};
  }

#pragma unroll
  for (int qc = 0; qc < 2; ++qc) {
    bf16* orow = Oh + ((size_t)b * L_ + q0w + qc * 16) * D_ + h * HD_;
#pragma unroll
    for (int t8 = 0; t8 < 8; ++t8)
#pragma unroll
      for (int r = 0; r < 4; ++r)
        orow[(size_t)(lg * 4 + r) * D_ + t8 * 16 + l15] = (bf16)oacc[qc][t8][r];
  }
}

// ---------------- host ----------------
extern "C" void kernel_launch(void* const* d_in, const int* in_sizes, int n_in,
                              void* d_out, int out_size, void* d_ws, size_t ws_size,
                              hipStream_t stream) {
  const float* x_q  = (const float*)d_in[0];
  const float* x_kv = (const float*)d_in[1];
  const float* w_q = (const float*)d_in[3];
  const float* w_k = (const float*)d_in[4];
  const float* w_v = (const float*)d_in[5];
  const float* w_o = (const float*)d_in[6];

  char* p = (char*)d_ws;
  auto alloc = [&](size_t bytes) { char* r = p; p += (bytes + 255) & ~(size_t)255; return r; };
  bf16* xq_b  = (bf16*)alloc((size_t)E_ * 2);
  bf16* xkv_b = (bf16*)alloc((size_t)E_ * 2);
  bf16* wq_b  = (bf16*)alloc((size_t)W_ * 2);
  bf16* wk_b  = (bf16*)alloc((size_t)W_ * 2);
  bf16* wv_b  = (bf16*)alloc((size_t)W_ * 2);
  bf16* wo_b  = (bf16*)alloc((size_t)W_ * 2);
  bf16* Qraw  = (bf16*)alloc((size_t)E_ * 2);
  bf16* Kraw  = (bf16*)alloc((size_t)E_ * 2);
  bf16* Vt    = (bf16*)alloc((size_t)E_ * 2);
  bf16* Oh    = (bf16*)alloc((size_t)E_ * 2);
  float* ct   = (float*)alloc((size_t)L_ * 64 * 4);
  float* st2  = (float*)alloc((size_t)L_ * 64 * 4);

  float* out0     = (float*)d_out;
  float* attn_out = out0 + E_;

  prep<<<33280, 256, 0, stream>>>(x_q, x_kv, w_q, w_k, w_v, w_o,
                                  xq_b, xkv_b, wq_b, wk_b, wv_b, wo_b, ct, st2);
  gemm_qkv<<<dim3(48, 32), 256, 0, stream>>>(xq_b, xkv_b, wq_b, wk_b, wv_b,
                                             ct, st2, Qraw, Kraw, Vt);
  attn_fused<<<dim3(16, 32), 256, 0, stream>>>(Qraw, Kraw, Vt, attn_out, Oh);
  gemm_bt<<<dim3(16, 32), 256, 0, stream>>>(Oh, wo_b, out0, B_*L_, D_, D_);
}